// Round 6
// baseline (477.666 us; speedup 1.0000x reference)
//
#include <hip/hip_runtime.h>
#include <math.h>

// Problem constants
#define L4   4
#define CPL  1024
#define HID  1024
#define IND  512
#define MLPD 128
#define OUTD 512
#define G3   3072
#define ROWS 4096   // L4*CPL
#define KP   544    // padded gi K: 512 OUT + 1 tension + 31 zeros
#define SCL  0.0009765625f   // 1/1024, exact pow2

typedef unsigned short u16;
typedef u16   u16x8  __attribute__((ext_vector_type(8)));
typedef short bf16x8 __attribute__((ext_vector_type(8)));
typedef float f32x4  __attribute__((ext_vector_type(4)));

__device__ __forceinline__ float b2f(u16 u) {
  return __uint_as_float(((unsigned int)u) << 16);
}
__device__ __forceinline__ u16 f2b(float f) {   // round-to-nearest-even
  unsigned int x = __float_as_uint(f);
  x += 0x7fffu + ((x >> 16) & 1u);
  return (u16)(x >> 16);
}
__device__ __forceinline__ float sigm(float v) { return 1.0f/(1.0f + expf(-v)); }

// ---- dual-dtype access helpers: f32 flag selects float32 vs bf16 layout ----
__device__ __forceinline__ float ld1(const void* p, size_t i, bool f32) {
  return f32 ? ((const float*)p)[i] : b2f(((const u16*)p)[i]);
}
__device__ __forceinline__ void st1(void* p, size_t i, float v, bool f32) {
  if (f32) ((float*)p)[i] = v; else ((u16*)p)[i] = f2b(v);
}
// load 8 elems -> bf16 bits (converting if fp32). i must be multiple of 8.
__device__ __forceinline__ u16x8 ldc8(const void* p, size_t i, bool f32) {
  u16x8 r;
  if (f32) {
    const float* q = (const float*)p + i;
    float4 v0 = *reinterpret_cast<const float4*>(q);
    float4 v1 = *reinterpret_cast<const float4*>(q + 4);
    r[0]=f2b(v0.x); r[1]=f2b(v0.y); r[2]=f2b(v0.z); r[3]=f2b(v0.w);
    r[4]=f2b(v1.x); r[5]=f2b(v1.y); r[6]=f2b(v1.z); r[7]=f2b(v1.w);
  } else {
    r = *reinterpret_cast<const u16x8*>((const u16*)p + i);
  }
  return r;
}

// ---------------- dtype detector ----------------
__global__ void k_detect(const void* __restrict__ x, int* __restrict__ flag) {
  int t = threadIdx.x;   // 256
  const u16* xu = (const u16*)x;
  unsigned u = xu[2*t];
  int e = (u >> 7) & 0xFF;
  int good = (e >= 96 && e <= 134) ? 1 : 0;
  __shared__ int cnt[256];
  cnt[t] = good;
  __syncthreads();
  for (int s = 128; s > 0; s >>= 1) { if (t < s) cnt[t] += cnt[t+s]; __syncthreads(); }
  if (t == 0) flag[0] = (cnt[0] < 200) ? 1 : 0;   // 1 = float32, 0 = bf16
}

// ---------------- prep: zero accumulators + bias sums ----------------
__global__ void k_prep(float* __restrict__ zf, const void* __restrict__ bih,
                       const void* __restrict__ bhh, const int* __restrict__ dflag,
                       float* __restrict__ bs_r, float* __restrict__ bs_z,
                       float* __restrict__ bn_i, float* __restrict__ bn_h) {
  const bool f32 = dflag[0] != 0;
  int b = blockIdx.x, t = threadIdx.x;
  if (b < 16) {
    int idx = b*256 + t;          // [0,4096)
    int l = idx >> 10, j = idx & 1023;
    bs_r[idx] = ld1(bih, l*G3 + j, f32)        + ld1(bhh, l*G3 + j, f32);
    bs_z[idx] = ld1(bih, l*G3 + 1024 + j, f32) + ld1(bhh, l*G3 + 1024 + j, f32);
    bn_i[idx] = ld1(bih, l*G3 + 2048 + j, f32);
    bn_h[idx] = ld1(bhh, l*G3 + 2048 + j, f32);
  } else {
    int idx = (b-16)*256 + t;     // [0,12288)
    zf[idx] = 0.0f;
  }
}

// ---------------- repack Wih -> bf16 [4][3072][544] (col 512 = tension wt) ----
__global__ void k_prep_wih(const void* __restrict__ Wih, const int* __restrict__ dflag,
                           u16* __restrict__ WihP) {
  const bool f32 = dflag[0] != 0;
  int row = blockIdx.x;            // 0..12287 == l*3072+g
  int t = threadIdx.x;
  size_t src = (size_t)row * 513;
  size_t dst = (size_t)row * KP;
  WihP[dst + t]       = f2b(ld1(Wih, src + t, f32));
  WihP[dst + 256 + t] = f2b(ld1(Wih, src + 256 + t, f32));
  if (t < 32) {
    float v = (t == 0) ? ld1(Wih, src + 512, f32) : 0.0f;
    WihP[dst + 512 + t] = f2b(v);
  }
}

// ---------------- convert Whh -> WhhP and hiddens -> HB (bf16), one launch ----
__global__ void k_prep_cvt(const void* __restrict__ Whh, const void* __restrict__ H,
                           const int* __restrict__ dflag,
                           u16* __restrict__ WhhP, u16* __restrict__ HB) {
  const bool f32 = dflag[0] != 0;
  int t = threadIdx.x;
  int b = blockIdx.x;                      // [0, 8192): 6144 Whh + 2048 HB
  int c8 = (t & 127) * 8;
  if (b < 6144) {
    int row = b*2 + (t >> 7);              // [0,12288)
    size_t off = (size_t)row * HID + c8;
    *reinterpret_cast<u16x8*>(&WhhP[off]) = ldc8(Whh, off, f32);
  } else {
    int row = (b - 6144)*2 + (t >> 7);     // [0,4096)
    size_t off = (size_t)row * HID + c8;
    *reinterpret_cast<u16x8*>(&HB[off]) = ldc8(H, off, f32);
  }
}

// ---------------- repack W1 hidden part -> bf16 transposed W1T[l][path*128+m][k] ----
// src: W1[l][512+k][m]  (k in [0,1024), m in [0,128)).  64-k-row tiles, 128 blocks.
__global__ void k_prep_w1t(const void* __restrict__ eaW1, const void* __restrict__ egW1,
                           const int* __restrict__ dflag, u16* __restrict__ W1T) {
  const bool f32 = dflag[0] != 0;
  __shared__ u16 sT[128*66];
  int l = blockIdx.x, path = blockIdx.y, kt = blockIdx.z;   // (4,2,16)
  int t = threadIdx.x;
  const void* W1 = path ? egW1 : eaW1;
  // read 64 k-rows x 128 m (coalesced over m), store transposed in LDS
  for (int rr = 0; rr < 64; rr += 2) {
    int r = rr + (t >> 7), m = t & 127;
    float v = ld1(W1, ((size_t)l*1536 + 512 + kt*64 + r)*MLPD + m, f32);
    sT[m*66 + r] = f2b(v);
  }
  __syncthreads();
  // write rows of W1T (coalesced over k)
  for (int mm = 0; mm < 128; mm += 4) {
    int m = mm + (t >> 6), kk = t & 63;
    W1T[((size_t)l*256 + path*128 + m)*1024 + kt*64 + kk] = sT[m*66 + kk];
  }
}

// ---------------- pack W2 -> bf16 NT W2M[l][o(512)][k(256)] ----------------
// k<128: W2a[l][k][o];  k>=128: -W2g[l][k-128][o]  (sign folded here).
__global__ void k_prep_w2m(const void* __restrict__ eaW2, const void* __restrict__ egW2,
                           const int* __restrict__ dflag, u16* __restrict__ W2M) {
  const bool f32 = dflag[0] != 0;
  __shared__ u16 sT[128*130];
  int l = blockIdx.x, path = blockIdx.y, ot = blockIdx.z;   // (4,2,4)
  int t = threadIdx.x;
  const void* W2 = path ? egW2 : eaW2;
  float sgn = path ? -1.0f : 1.0f;
  // read 128 m-rows x 128 o (coalesced over o), store transposed in LDS
  for (int rr = 0; rr < 128; rr += 2) {
    int r = rr + (t >> 7), o = t & 127;
    float v = ld1(W2, ((size_t)l*MLPD + r)*OUTD + ot*128 + o, f32);
    sT[o*130 + r] = f2b(sgn*v);
  }
  __syncthreads();
  // write rows of W2M (coalesced over m/k)
  for (int oo = 0; oo < 128; oo += 2) {
    int o = oo + (t >> 7), m = t & 127;
    W2M[((size_t)l*OUTD + ot*128 + o)*256 + path*128 + m] = sT[o*130 + m];
  }
}

// ---------------- base accumulation (x part of encoder layer 1) ----------------
__global__ void k_base_acc(const void* __restrict__ x, const void* __restrict__ eaW1,
                           const void* __restrict__ egW1, const int* __restrict__ dflag,
                           float* __restrict__ baseacc) {
  const bool f32 = dflag[0] != 0;
  int l = blockIdx.x, path = blockIdx.y, kc = blockIdx.z, m = threadIdx.x; // 128 thr
  const void* W1 = path ? egW1 : eaW1;
  float acc = 0.0f;
  int i0 = kc*128;
  for (int i = i0; i < i0 + 128; ++i)
    acc += ld1(x, i, f32) * ld1(W1, ((size_t)l*1536 + i)*MLPD + m, f32);
  atomicAdd(&baseacc[path*512 + l*MLPD + m], acc);
}

#define SWZ(row, ku) ((row)*64 + ((ku) ^ (((row)&7)<<3)))

// ---------------- MFMA k_z v3: Z = relu(base + b1 + HB @ W1T^T) ----------------
// 64x64 tile, 4 waves 2x2 (32x32 each), BK=64, dbuf, SWZ, 1 raw barrier/step.
__global__ __launch_bounds__(256) void k_z_mfma(
    const u16* __restrict__ HB, const u16* __restrict__ W1T,
    const void* __restrict__ eab1, const void* __restrict__ egb1,
    const float* __restrict__ baseacc, const int* __restrict__ dflag,
    u16* __restrict__ Z) {
  const bool f32 = dflag[0] != 0;
  __shared__ __align__(16) u16 sA[2][64*64];
  __shared__ __align__(16) u16 sB[2][64*64];
  int t = threadIdx.x;
  int row0 = blockIdx.x * 64;
  int n0   = blockIdx.y * 64;          // 0,64,128,192
  int l    = row0 >> 10;
  int wid = t >> 6, lane = t & 63;
  int waveM = wid >> 1, waveN = wid & 1;
  int quad = lane >> 4, lcol = lane & 15;

  f32x4 acc[2][2];
  const f32x4 zz = {0.0f,0.0f,0.0f,0.0f};
#pragma unroll
  for (int i = 0; i < 2; ++i)
#pragma unroll
    for (int j = 0; j < 2; ++j) acc[i][j] = zz;

  u16x8 ra[2], rb[2];
  auto loadk = [&](int k0) {
#pragma unroll
    for (int s = 0; s < 2; ++s) {
      int idx = s*256 + t, row = idx >> 3, ch = idx & 7;
      ra[s] = *reinterpret_cast<const u16x8*>(
          HB + (size_t)(row0 + row)*HID + k0 + ch*8);
      rb[s] = *reinterpret_cast<const u16x8*>(
          W1T + ((size_t)l*256 + n0 + row)*1024 + k0 + ch*8);
    }
  };
  auto stage = [&](int cb) {
#pragma unroll
    for (int s = 0; s < 2; ++s) {
      int idx = s*256 + t, row = idx >> 3, ch = idx & 7;
      *reinterpret_cast<u16x8*>(&sA[cb][SWZ(row, ch*8)]) = ra[s];
      *reinterpret_cast<u16x8*>(&sB[cb][SWZ(row, ch*8)]) = rb[s];
    }
  };

  int cur = 0;
  loadk(0);
  for (int k0 = 0; k0 < HID; k0 += 64) {
    stage(cur);
    asm volatile("s_waitcnt lgkmcnt(0)" ::: "memory");
    __builtin_amdgcn_s_barrier();
    if (k0 + 64 < HID) loadk(k0 + 64);
    __builtin_amdgcn_s_setprio(1);
#pragma unroll
    for (int kc = 0; kc < 2; ++kc) {
      bf16x8 af[2];
#pragma unroll
      for (int i = 0; i < 2; ++i) {
        int rl = waveM*32 + i*16 + lcol;
        af[i] = *reinterpret_cast<const bf16x8*>(&sA[cur][SWZ(rl, kc*32 + quad*8)]);
      }
#pragma unroll
      for (int j = 0; j < 2; ++j) {
        int jl = waveN*32 + j*16 + lcol;
        bf16x8 bf = *reinterpret_cast<const bf16x8*>(&sB[cur][SWZ(jl, kc*32 + quad*8)]);
#pragma unroll
        for (int i = 0; i < 2; ++i)
          acc[i][j] = __builtin_amdgcn_mfma_f32_16x16x32_bf16(af[i], bf, acc[i][j], 0, 0, 0);
      }
    }
    __builtin_amdgcn_s_setprio(0);
    cur ^= 1;
  }
  // epilogue: + base + b1, relu, store
#pragma unroll
  for (int j = 0; j < 2; ++j) {
    int nn = n0 + waveN*32 + j*16 + lcol;
    int path = nn >> 7, m = nn & 127;
    float bval = baseacc[path*512 + l*MLPD + m] +
                 ld1(path ? egb1 : eab1, l*MLPD + m, f32);
#pragma unroll
    for (int i = 0; i < 2; ++i)
#pragma unroll
      for (int g = 0; g < 4; ++g) {
        int r = row0 + waveM*32 + i*16 + quad*4 + g;
        float v = acc[i][j][g] + bval;
        Z[(size_t)r*256 + nn] = f2b(v > 0.0f ? v : 0.0f);
      }
  }
}

// ---------------- MFMA k_outm: OUT = Zb @ W2M^T + (b2a-b2g) ----------------
// M=4096, N=512, K=256. 128x64 tile, 4 waves (2Mx2J), BK=64, dbuf, SWZ.
__global__ __launch_bounds__(256) void k_outm(
    const u16* __restrict__ Zb, const u16* __restrict__ W2M,
    const void* __restrict__ eab2, const void* __restrict__ egb2,
    const int* __restrict__ dflag, u16* __restrict__ OUTT) {
  const bool f32 = dflag[0] != 0;
  __shared__ __align__(16) u16 sA[2][128*64];   // 32 KB
  __shared__ __align__(16) u16 sB[2][64*64];    // 16 KB
  int t = threadIdx.x;
  int row0 = blockIdx.x * 128;
  int n0   = blockIdx.y * 64;
  int l    = row0 >> 10;
  int wid = t >> 6, lane = t & 63;
  int waveM = wid & 1, waveJ = wid >> 1;
  int quad = lane >> 4, lcol = lane & 15;

  f32x4 acc[4][2];
  const f32x4 zz = {0.0f,0.0f,0.0f,0.0f};
#pragma unroll
  for (int i = 0; i < 4; ++i)
#pragma unroll
    for (int j = 0; j < 2; ++j) acc[i][j] = zz;

  u16x8 ra[4], rb[2];
  auto loadk = [&](int k0) {
#pragma unroll
    for (int s = 0; s < 4; ++s) {
      int idx = s*256 + t, row = idx >> 3, ch = idx & 7;
      ra[s] = *reinterpret_cast<const u16x8*>(
          Zb + (size_t)(row0 + row)*256 + k0 + ch*8);
    }
#pragma unroll
    for (int s = 0; s < 2; ++s) {
      int idx = s*256 + t, row = idx >> 3, ch = idx & 7;
      rb[s] = *reinterpret_cast<const u16x8*>(
          W2M + ((size_t)l*OUTD + n0 + row)*256 + k0 + ch*8);
    }
  };
  auto stage = [&](int cb) {
#pragma unroll
    for (int s = 0; s < 4; ++s) {
      int idx = s*256 + t, row = idx >> 3, ch = idx & 7;
      *reinterpret_cast<u16x8*>(&sA[cb][SWZ(row, ch*8)]) = ra[s];
    }
#pragma unroll
    for (int s = 0; s < 2; ++s) {
      int idx = s*256 + t, row = idx >> 3, ch = idx & 7;
      *reinterpret_cast<u16x8*>(&sB[cb][SWZ(row, ch*8)]) = rb[s];
    }
  };

  int cur = 0;
  loadk(0);
  for (int k0 = 0; k0 < 256; k0 += 64) {
    stage(cur);
    asm volatile("s_waitcnt lgkmcnt(0)" ::: "memory");
    __builtin_amdgcn_s_barrier();
    if (k0 + 64 < 256) loadk(k0 + 64);
    __builtin_amdgcn_s_setprio(1);
#pragma unroll
    for (int kc = 0; kc < 2; ++kc) {
      bf16x8 af[4];
#pragma unroll
      for (int i = 0; i < 4; ++i) {
        int rl = waveM*64 + i*16 + lcol;
        af[i] = *reinterpret_cast<const bf16x8*>(&sA[cur][SWZ(rl, kc*32 + quad*8)]);
      }
#pragma unroll
      for (int jj = 0; jj < 2; ++jj) {
        int jl = waveJ*32 + jj*16 + lcol;
        bf16x8 bf = *reinterpret_cast<const bf16x8*>(&sB[cur][SWZ(jl, kc*32 + quad*8)]);
#pragma unroll
        for (int i = 0; i < 4; ++i)
          acc[i][jj] = __builtin_amdgcn_mfma_f32_16x16x32_bf16(af[i], bf, acc[i][jj], 0, 0, 0);
      }
    }
    __builtin_amdgcn_s_setprio(0);
    cur ^= 1;
  }
  // epilogue: + bias diff, store bf16 into OUTT
#pragma unroll
  for (int jj = 0; jj < 2; ++jj) {
    int o = n0 + waveJ*32 + jj*16 + lcol;
    float bd = ld1(eab2, l*OUTD + o, f32) - ld1(egb2, l*OUTD + o, f32);
#pragma unroll
    for (int i = 0; i < 4; ++i)
#pragma unroll
      for (int g = 0; g < 4; ++g) {
        int r = row0 + waveM*64 + i*16 + quad*4 + g;
        OUTT[(size_t)r*KP + o] = f2b(acc[i][jj][g] + bd);
      }
  }
}

// tension -> OUTT col 512 (bf16); zero pad cols 513..543; tsum += sumsq(row)
__global__ void k_tension(u16* __restrict__ OUTT, float* __restrict__ tsum) {
  int row = blockIdx.x, t = threadIdx.x;
  u16* p = OUTT + (size_t)row*KP;
  float v0 = b2f(p[t]), v1 = b2f(p[t+256]);
  float s = v0*v0 + v1*v1;
#pragma unroll
  for (int off = 32; off > 0; off >>= 1) s += __shfl_down(s, off, 64);
  __shared__ float red[4];
  if ((t & 63) == 0) red[t >> 6] = s;
  __syncthreads();
  if (t == 0) {
    float tot = red[0] + red[1] + red[2] + red[3];
    p[512] = f2b(tot * (1.0f/512.0f));
    atomicAdd(tsum, tot);
  }
  if (t < 31) p[513 + t] = 0;
}

// ---------------- fused MFMA GRU (exact R3 version: proven 62 us) ----------
__global__ __launch_bounds__(256, 2) void k_gru_mfma(
    const u16* __restrict__ OUTT, const u16* __restrict__ HB,
    const u16* __restrict__ WihP, const u16* __restrict__ WhhP,
    const void* __restrict__ H,
    const float* __restrict__ bs_r, const float* __restrict__ bs_z,
    const float* __restrict__ bn_i, const float* __restrict__ bn_h,
    const int* __restrict__ dflag, void* __restrict__ outv) {
  const bool f32 = dflag[0] != 0;
  __shared__ __align__(16) u16 sA[2][128*64];     // 32 KB
  __shared__ __align__(16) u16 sB[2][3*64*64];    // 48 KB  (80 KB total, 2 blk/CU)
  int t = threadIdx.x;
  // XCD swizzle (512 blocks, 512%8==0 -> bijective): xg = XCD id.
  int bid = blockIdx.x;
  int xg = bid & 7, inner = bid >> 3;      // inner 0..63
  int l = xg & 3, jG = xg >> 2;
  int rbi = inner & 7, jbl = inner >> 3;   // 8 row-blocks, 8 j-blocks
  int row0 = (l*8 + rbi) * 128;
  int j0   = (jG*8 + jbl) * 64;
  int wid = t >> 6, lane = t & 63;
  int waveM = wid & 1, waveJ = wid >> 1;   // 2x2 waves over 128x64
  int quad = lane >> 4, lcol = lane & 15;

  f32x4 acc[4][4][2];   // band {r,z,i_n,h_n} x 4 m-frags x 2 j-frags
  const f32x4 zz = {0.0f,0.0f,0.0f,0.0f};
#pragma unroll
  for (int b = 0; b < 4; ++b)
#pragma unroll
    for (int i = 0; i < 4; ++i)
#pragma unroll
      for (int j = 0; j < 2; ++j) acc[b][i][j] = zz;

  u16x8 ra[4], rbr[6];
  auto load1 = [&](int k0) {           // GEMM1 sources (zero-pad K tail)
    int kw = KP - k0;                  // 64 except last step (32)
#pragma unroll
    for (int s = 0; s < 4; ++s) {
      int idx = s*256 + t, row = idx >> 3, ch = idx & 7;
      if (ch*8 < kw)
        ra[s] = *reinterpret_cast<const u16x8*>(
            OUTT + (size_t)(row0 + row)*KP + k0 + ch*8);
      else { u16x8 z = {0,0,0,0,0,0,0,0}; ra[s] = z; }
    }
#pragma unroll
    for (int s = 0; s < 6; ++s) {
      int idx = s*256 + t, band = idx >> 9, rem = idx & 511;
      int row = rem >> 3, ch = rem & 7;
      if (ch*8 < kw)
        rbr[s] = *reinterpret_cast<const u16x8*>(
            WihP + ((size_t)l*G3 + band*1024 + j0 + row)*KP + k0 + ch*8);
      else { u16x8 z = {0,0,0,0,0,0,0,0}; rbr[s] = z; }
    }
  };
  auto load2 = [&](int k0) {           // GEMM2 sources (pure bf16)
#pragma unroll
    for (int s = 0; s < 4; ++s) {
      int idx = s*256 + t, row = idx >> 3, ch = idx & 7;
      ra[s] = *reinterpret_cast<const u16x8*>(
          HB + (size_t)(row0 + row)*HID + k0 + ch*8);
    }
#pragma unroll
    for (int s = 0; s < 6; ++s) {
      int idx = s*256 + t, band = idx >> 9, rem = idx & 511;
      int row = rem >> 3, ch = rem & 7;
      rbr[s] = *reinterpret_cast<const u16x8*>(
          WhhP + ((size_t)l*G3 + band*1024 + j0 + row)*HID + k0 + ch*8);
    }
  };
  auto stage = [&](int cb) {
#pragma unroll
    for (int s = 0; s < 4; ++s) {
      int idx = s*256 + t, row = idx >> 3, ch = idx & 7;
      *reinterpret_cast<u16x8*>(&sA[cb][SWZ(row, ch*8)]) = ra[s];
    }
#pragma unroll
    for (int s = 0; s < 6; ++s) {
      int idx = s*256 + t, band = idx >> 9, rem = idx & 511;
      int row = rem >> 3, ch = rem & 7;
      *reinterpret_cast<u16x8*>(&sB[cb][band*4096 + SWZ(row, ch*8)]) = rbr[s];
    }
  };

  int cur = 0;
  // ---- GEMM1: gi over K=544 ----
  load1(0);
  for (int k0 = 0; k0 < KP; k0 += 64) {
    stage(cur);
    asm volatile("s_waitcnt lgkmcnt(0)" ::: "memory");
    __builtin_amdgcn_s_barrier();
    if (k0 + 64 < KP) load1(k0 + 64);
    else              load2(0);               // bridge into GEMM2
    __builtin_amdgcn_s_setprio(1);
#pragma unroll
    for (int kc = 0; kc < 2; ++kc) {
      bf16x8 af[4];
#pragma unroll
      for (int i = 0; i < 4; ++i) {
        int rl = waveM*64 + i*16 + lcol;
        af[i] = *reinterpret_cast<const bf16x8*>(&sA[cur][SWZ(rl, kc*32 + quad*8)]);
      }
#pragma unroll
      for (int b = 0; b < 3; ++b)
#pragma unroll
        for (int jj = 0; jj < 2; ++jj) {
          int jl = waveJ*32 + jj*16 + lcol;
          bf16x8 bf = *reinterpret_cast<const bf16x8*>(
              &sB[cur][b*4096 + SWZ(jl, kc*32 + quad*8)]);
#pragma unroll
          for (int i = 0; i < 4; ++i)
            acc[b][i][jj] = __builtin_amdgcn_mfma_f32_16x16x32_bf16(
                af[i], bf, acc[b][i][jj], 0, 0, 0);
        }
    }
    __builtin_amdgcn_s_setprio(0);
    cur ^= 1;
  }
  // ---- GEMM2: gh over K=1024 ----
  for (int k0 = 0; k0 < HID; k0 += 64) {
    stage(cur);
    asm volatile("s_waitcnt lgkmcnt(0)" ::: "memory");
    __builtin_amdgcn_s_barrier();
    if (k0 + 64 < HID) load2(k0 + 64);
    __builtin_amdgcn_s_setprio(1);
#pragma unroll
    for (int kc = 0; kc < 2; ++kc) {
      bf16x8 af[4];
#pragma unroll
      for (int i = 0; i < 4; ++i) {
        int rl = waveM*64 + i*16 + lcol;
        af[i] = *reinterpret_cast<const bf16x8*>(&sA[cur][SWZ(rl, kc*32 + quad*8)]);
      }
#pragma unroll
      for (int b = 0; b < 3; ++b) {
        int ai = (b < 2) ? b : 3;
#pragma unroll
        for (int jj = 0; jj < 2; ++jj) {
          int jl = waveJ*32 + jj*16 + lcol;
          bf16x8 bf = *reinterpret_cast<const bf16x8*>(
              &sB[cur][b*4096 + SWZ(jl, kc*32 + quad*8)]);
#pragma unroll
          for (int i = 0; i < 4; ++i)
            acc[ai][i][jj] = __builtin_amdgcn_mfma_f32_16x16x32_bf16(
                af[i], bf, acc[ai][i][jj], 0, 0, 0);
        }
      }
    }
    __builtin_amdgcn_s_setprio(0);
    cur ^= 1;
  }
  // ---- epilogue: gates -> new_h into d_out hh region (exact f32 h blend) ----
#pragma unroll
  for (int i = 0; i < 4; ++i)
#pragma unroll
    for (int jj = 0; jj < 2; ++jj) {
      int j = j0 + waveJ*32 + jj*16 + lcol;
      float br = bs_r[l*HID + j], bz = bs_z[l*HID + j];
      float bi = bn_i[l*HID + j], bh = bn_h[l*HID + j];
#pragma unroll
      for (int g = 0; g < 4; ++g) {
        int r = row0 + waveM*64 + i*16 + quad*4 + g;
        float rg = sigm(acc[0][i][jj][g] + br);
        float zg = sigm(acc[1][i][jj][g] + bz);
        float ng = tanhf(acc[2][i][jj][g] + bi + rg*(acc[3][i][jj][g] + bh));
        float hv = ld1(H, (size_t)r*HID + j, f32);
        st1(outv, 513 + (size_t)r*HID + j, (1.0f - zg)*ng + zg*hv, f32);
      }
    }
}

// ---------------- level means (split-C atomics; lm holds SUMS, scaled by consumers) ----
__global__ void k_lm_acc(const void* __restrict__ outv, const int* __restrict__ dflag,
                         float* __restrict__ lm) {
  const bool f32 = dflag[0] != 0;
  int l = blockIdx.x, cc = blockIdx.y, t = threadIdx.x;
  float s0=0.f, s1=0.f, s2=0.f, s3=0.f;
  for (int c = cc*16; c < cc*16 + 16; ++c) {
    size_t base = 513 + (size_t)(l*CPL + c)*HID;
    s0 += ld1(outv, base + t,       f32);
    s1 += ld1(outv, base + 256 + t, f32);
    s2 += ld1(outv, base + 512 + t, f32);
    s3 += ld1(outv, base + 768 + t, f32);
  }
  atomicAdd(&lm[l*HID + t],       s0);
  atomicAdd(&lm[l*HID + 256 + t], s1);
  atomicAdd(&lm[l*HID + 512 + t], s2);
  atomicAdd(&lm[l*HID + 768 + t], s3);
}

// ---------------- predictors (split-K atomics; SCL folds the 1/1024 mean) ----
__global__ void k_pz_acc(const float* __restrict__ lm, const void* __restrict__ pW1,
                         const int* __restrict__ dflag, float* __restrict__ pz) {
  const bool f32 = dflag[0] != 0;
  int lv = blockIdx.x, mb = blockIdx.y, kc = blockIdx.z;
  int m = mb*256 + threadIdx.x;
  float acc = 0.0f;
  int i0 = kc*32;
  const float* lmp = lm + (lv + 1)*HID;
  for (int i = i0; i < i0 + 32; ++i)
    acc += lmp[i] * ld1(pW1, ((size_t)lv*HID + i)*HID + m, f32);
  atomicAdd(&pz[lv*HID + m], acc * SCL);
}
__global__ void k_pzfin(float* __restrict__ pz, const void* __restrict__ pb1,
                        const int* __restrict__ dflag) {
  const bool f32 = dflag[0] != 0;
  int idx = blockIdx.x*256 + threadIdx.x;   // [0,3072)
  float v = pz[idx] + ld1(pb1, idx, f32);
  pz[idx] = v > 0.0f ? v : 0.0f;
}
__global__ void k_pe_acc(const float* __restrict__ pz, const void* __restrict__ pW2,
                         const int* __restrict__ dflag, float* __restrict__ pe) {
  const bool f32 = dflag[0] != 0;
  int lv = blockIdx.x, ob = blockIdx.y, kc = blockIdx.z;
  int o = ob*256 + threadIdx.x;
  float acc = 0.0f;
  int m0 = kc*32;
  const float* pzp = pz + lv*HID;
  for (int m = m0; m < m0 + 32; ++m)
    acc += pzp[m] * ld1(pW2, ((size_t)lv*HID + m)*HID + o, f32);
  atomicAdd(&pe[lv*HID + o], acc);
}
__global__ void k_pefin(float* __restrict__ pe, const void* __restrict__ pb2,
                        const float* __restrict__ lm, const int* __restrict__ dflag) {
  const bool f32 = dflag[0] != 0;
  int idx = blockIdx.x*256 + threadIdx.x;   // [0,3072)
  pe[idx] = (pe[idx] + ld1(pb2, idx, f32) - lm[idx]*SCL) * 0.05f;
}

__global__ void k_addc_gop(const float* __restrict__ lm, const float* __restrict__ pe,
                           float* __restrict__ addc, float* __restrict__ gop) {
  int j = blockIdx.x*256 + threadIdx.x;
  float pe0 = pe[j], pe1 = pe[1024 + j], pe2 = pe[2048 + j];
  float d0 = pe0, d1 = pe1 - 0.5f*pe0, d2 = pe2 - 0.5f*pe1, d3 = -0.5f*pe2;
  float l0 = lm[j]*SCL, l1 = lm[1024 + j]*SCL, l2 = lm[2048 + j]*SCL, l3 = lm[3072 + j]*SCL;
  addc[j]        = 0.2775f*l0 + d0;
  addc[1024 + j] = 0.2775f*l1 + d1;
  addc[2048 + j] = 0.2775f*l2 + d2;
  addc[3072 + j] = 0.2775f*l3 + d3;
  gop[j] = 0.25f*((l0 + d0) + (l1 + d1) + (l2 + d2) + (l3 + d3));
}

__global__ void k_comb_acc(const float* __restrict__ lm, const void* __restrict__ peiW,
                           const int* __restrict__ dflag, float* __restrict__ comb) {
  const bool f32 = dflag[0] != 0;
  int ob = blockIdx.x, kc = blockIdx.y;
  int o = ob*256 + threadIdx.x;
  float acc = 0.0f;
  int i0 = kc*128;
  for (int i = i0; i < i0 + 128; ++i)
    acc += lm[i] * ld1(peiW, (size_t)i*OUTD + o, f32);
  atomicAdd(&comb[o], acc * SCL);
}
__global__ void k_fin(const float* __restrict__ comb, const void* __restrict__ peib,
                      const float* __restrict__ tsum, const int* __restrict__ dflag,
                      void* __restrict__ outv) {
  const bool f32 = dflag[0] != 0;
  int o = blockIdx.x*256 + threadIdx.x;
  st1(outv, o, comb[o] + ld1(peib, o, f32), f32);
  if (o == 0) st1(outv, 512, tsum[0] * (1.0f/(4096.0f*512.0f)), f32);
}

__global__ void k_hh(void* __restrict__ outv, const float* __restrict__ addc,
                     const float* __restrict__ gop, const int* __restrict__ step,
                     const int* __restrict__ dflag) {
  const bool f32 = dflag[0] != 0;
  int row = blockIdx.x, t = threadIdx.x;
  int l = row >> 10, c = row & 1023;
  bool debate = (step[0] > 5) && (c < 256);
  size_t base = 513 + (size_t)row*HID;
#pragma unroll
  for (int k = 0; k < 4; ++k) {
    int j = t + k*256;
    float v = 0.7225f * ld1(outv, base + j, f32) + addc[l*HID + j];
    if (debate) v = 0.85f*v + 0.15f*gop[j];
    st1(outv, base + j, v, f32);
  }
}

extern "C" void kernel_launch(void* const* d_in, const int* in_sizes, int n_in,
                              void* d_out, int out_size, void* d_ws, size_t ws_size,
                              hipStream_t stream) {
  (void)in_sizes; (void)n_in; (void)out_size; (void)ws_size;
  const void* x    = d_in[0];
  const void* hid  = d_in[1];
  const void* eaW1 = d_in[2];
  const void* eab1 = d_in[3];
  const void* eaW2 = d_in[4];
  const void* eab2 = d_in[5];
  const void* egW1 = d_in[6];
  const void* egb1 = d_in[7];
  const void* egW2 = d_in[8];
  const void* egb2 = d_in[9];
  const void* gWih = d_in[10];
  const void* gWhh = d_in[11];
  const void* gbih = d_in[12];
  const void* gbhh = d_in[13];
  const void* pW1  = d_in[14];
  const void* pb1  = d_in[15];
  const void* pW2  = d_in[16];
  const void* pb2  = d_in[17];
  const void* peiW = d_in[18];
  const void* peib = d_in[19];
  const int*  step = (const int*)d_in[20];

  // ---- workspace layout (~54.6 MB) ----
  float* wsf = (float*)d_ws;
  float* tsum    = wsf + 0;       // 64
  float* baseacc = wsf + 64;      // 1024
  float* lm      = wsf + 1088;    // 4096
  float* pz      = wsf + 5184;    // 3072
  float* pe      = wsf + 8256;    // 3072
  float* comb    = wsf + 11328;   // 512 (+pad to 12288)
  int*   dflag   = (int*)(wsf + 12288);  // 64
  float* bs_r    = wsf + 12352;   // 4096
  float* bs_z    = wsf + 16448;   // 4096
  float* bn_i    = wsf + 20544;   // 4096
  float* bn_h    = wsf + 24640;   // 4096
  float* addc    = wsf + 28736;   // 4096
  float* gop     = wsf + 32832;   // 1024
  u16* Zb   = (u16*)(wsf + 33856);        // 4096*256
  u16* OUTT = Zb + (size_t)4096*256;      // 4096*544
  u16* WihP = OUTT + (size_t)4096*KP;     // 12288*544
  u16* HB   = WihP + (size_t)12288*KP;    // 4096*1024  (bf16 hiddens)
  u16* WhhP = HB   + (size_t)4096*1024;   // 12288*1024 (bf16 Whh)
  u16* W2M  = WhhP + (size_t)12288*1024;  // 4*512*256  (bf16 packed W2, 1 MB)
  // W1T (4*256*1024 u16 = 2.1 MB) overlays OUTT: dead once k_z finishes,
  // before k_outm writes OUTT.
  u16* W1T  = OUTT;

  k_detect   <<<dim3(1),        dim3(256), 0, stream>>>(x, dflag);
  k_prep     <<<dim3(64),       dim3(256), 0, stream>>>(wsf, gbih, gbhh, dflag,
                                                        bs_r, bs_z, bn_i, bn_h);
  k_prep_wih <<<dim3(12288),    dim3(256), 0, stream>>>(gWih, dflag, WihP);
  k_prep_cvt <<<dim3(8192),     dim3(256), 0, stream>>>(gWhh, hid, dflag, WhhP, HB);
  k_prep_w1t <<<dim3(4,2,16),   dim3(256), 0, stream>>>(eaW1, egW1, dflag, W1T);
  k_prep_w2m <<<dim3(4,2,4),    dim3(256), 0, stream>>>(eaW2, egW2, dflag, W2M);
  k_base_acc <<<dim3(4,2,4),    dim3(128), 0, stream>>>(x, eaW1, egW1, dflag, baseacc);
  k_z_mfma   <<<dim3(64,4),     dim3(256), 0, stream>>>(HB, W1T, eab1, egb1,
                                                        baseacc, dflag, Zb);
  k_outm     <<<dim3(32,8),     dim3(256), 0, stream>>>(Zb, W2M, eab2, egb2,
                                                        dflag, OUTT);
  k_tension  <<<dim3(4096),     dim3(256), 0, stream>>>(OUTT, tsum);
  k_gru_mfma <<<dim3(512),      dim3(256), 0, stream>>>(OUTT, HB, WihP, WhhP, hid,
                                                        bs_r, bs_z, bn_i, bn_h,
                                                        dflag, d_out);
  k_lm_acc   <<<dim3(4,64),     dim3(256), 0, stream>>>(d_out, dflag, lm);
  k_pz_acc   <<<dim3(3,4,32),   dim3(256), 0, stream>>>(lm, pW1, dflag, pz);
  k_pzfin    <<<dim3(12),       dim3(256), 0, stream>>>(pz, pb1, dflag);
  k_pe_acc   <<<dim3(3,4,32),   dim3(256), 0, stream>>>(pz, pW2, dflag, pe);
  k_pefin    <<<dim3(12),       dim3(256), 0, stream>>>(pe, pb2, lm, dflag);
  k_addc_gop <<<dim3(4),        dim3(256), 0, stream>>>(lm, pe, addc, gop);
  k_comb_acc <<<dim3(2,32),     dim3(256), 0, stream>>>(lm, peiW, dflag, comb);
  k_fin      <<<dim3(2),        dim3(256), 0, stream>>>(comb, peib, tsum, dflag, d_out);
  k_hh       <<<dim3(4096),     dim3(256), 0, stream>>>(d_out, addc, gop, step, dflag);
}

// Round 7
// 472.559 us; speedup vs baseline: 1.0108x; 1.0108x over previous
//
#include <hip/hip_runtime.h>
#include <math.h>

// Problem constants
#define L4   4
#define CPL  1024
#define HID  1024
#define IND  512
#define MLPD 128
#define OUTD 512
#define G3   3072
#define ROWS 4096   // L4*CPL
#define KP   544    // padded gi K: 512 OUT + 1 tension + 31 zeros
#define SCL  0.0009765625f   // 1/1024, exact pow2

typedef unsigned short u16;
typedef u16   u16x8  __attribute__((ext_vector_type(8)));
typedef short bf16x8 __attribute__((ext_vector_type(8)));
typedef float f32x4  __attribute__((ext_vector_type(4)));

__device__ __forceinline__ float b2f(u16 u) {
  return __uint_as_float(((unsigned int)u) << 16);
}
__device__ __forceinline__ u16 f2b(float f) {   // round-to-nearest-even
  unsigned int x = __float_as_uint(f);
  x += 0x7fffu + ((x >> 16) & 1u);
  return (u16)(x >> 16);
}
__device__ __forceinline__ float sigm(float v) { return 1.0f/(1.0f + expf(-v)); }

// ---- dual-dtype access helpers: f32 flag selects float32 vs bf16 layout ----
__device__ __forceinline__ float ld1(const void* p, size_t i, bool f32) {
  return f32 ? ((const float*)p)[i] : b2f(((const u16*)p)[i]);
}
__device__ __forceinline__ void st1(void* p, size_t i, float v, bool f32) {
  if (f32) ((float*)p)[i] = v; else ((u16*)p)[i] = f2b(v);
}
// load 8 elems -> bf16 bits (converting if fp32). i must be multiple of 8.
__device__ __forceinline__ u16x8 ldc8(const void* p, size_t i, bool f32) {
  u16x8 r;
  if (f32) {
    const float* q = (const float*)p + i;
    float4 v0 = *reinterpret_cast<const float4*>(q);
    float4 v1 = *reinterpret_cast<const float4*>(q + 4);
    r[0]=f2b(v0.x); r[1]=f2b(v0.y); r[2]=f2b(v0.z); r[3]=f2b(v0.w);
    r[4]=f2b(v1.x); r[5]=f2b(v1.y); r[6]=f2b(v1.z); r[7]=f2b(v1.w);
  } else {
    r = *reinterpret_cast<const u16x8*>((const u16*)p + i);
  }
  return r;
}

// ---------------- dtype detector ----------------
__global__ void k_detect(const void* __restrict__ x, int* __restrict__ flag) {
  int t = threadIdx.x;   // 256
  const u16* xu = (const u16*)x;
  unsigned u = xu[2*t];
  int e = (u >> 7) & 0xFF;
  int good = (e >= 96 && e <= 134) ? 1 : 0;
  __shared__ int cnt[256];
  cnt[t] = good;
  __syncthreads();
  for (int s = 128; s > 0; s >>= 1) { if (t < s) cnt[t] += cnt[t+s]; __syncthreads(); }
  if (t == 0) flag[0] = (cnt[0] < 200) ? 1 : 0;   // 1 = float32, 0 = bf16
}

// ---------------- prep: zero accumulators + bias sums ----------------
__global__ void k_prep(float* __restrict__ zf, const void* __restrict__ bih,
                       const void* __restrict__ bhh, const int* __restrict__ dflag,
                       float* __restrict__ bs_r, float* __restrict__ bs_z,
                       float* __restrict__ bn_i, float* __restrict__ bn_h) {
  const bool f32 = dflag[0] != 0;
  int b = blockIdx.x, t = threadIdx.x;
  if (b < 16) {
    int idx = b*256 + t;          // [0,4096)
    int l = idx >> 10, j = idx & 1023;
    bs_r[idx] = ld1(bih, l*G3 + j, f32)        + ld1(bhh, l*G3 + j, f32);
    bs_z[idx] = ld1(bih, l*G3 + 1024 + j, f32) + ld1(bhh, l*G3 + 1024 + j, f32);
    bn_i[idx] = ld1(bih, l*G3 + 2048 + j, f32);
    bn_h[idx] = ld1(bhh, l*G3 + 2048 + j, f32);
  } else {
    int idx = (b-16)*256 + t;     // [0,12288)
    zf[idx] = 0.0f;
  }
}

// ---------------- repack Wih -> bf16 [4][3072][544] (col 512 = tension wt) ----
__global__ void k_prep_wih(const void* __restrict__ Wih, const int* __restrict__ dflag,
                           u16* __restrict__ WihP) {
  const bool f32 = dflag[0] != 0;
  int row = blockIdx.x;            // 0..12287 == l*3072+g
  int t = threadIdx.x;
  size_t src = (size_t)row * 513;
  size_t dst = (size_t)row * KP;
  WihP[dst + t]       = f2b(ld1(Wih, src + t, f32));
  WihP[dst + 256 + t] = f2b(ld1(Wih, src + 256 + t, f32));
  if (t < 32) {
    float v = (t == 0) ? ld1(Wih, src + 512, f32) : 0.0f;
    WihP[dst + 512 + t] = f2b(v);
  }
}

// ---------------- convert Whh -> WhhP and hiddens -> HB (bf16), one launch ----
__global__ void k_prep_cvt(const void* __restrict__ Whh, const void* __restrict__ H,
                           const int* __restrict__ dflag,
                           u16* __restrict__ WhhP, u16* __restrict__ HB) {
  const bool f32 = dflag[0] != 0;
  int t = threadIdx.x;
  int b = blockIdx.x;                      // [0, 8192): 6144 Whh + 2048 HB
  int c8 = (t & 127) * 8;
  if (b < 6144) {
    int row = b*2 + (t >> 7);              // [0,12288)
    size_t off = (size_t)row * HID + c8;
    *reinterpret_cast<u16x8*>(&WhhP[off]) = ldc8(Whh, off, f32);
  } else {
    int row = (b - 6144)*2 + (t >> 7);     // [0,4096)
    size_t off = (size_t)row * HID + c8;
    *reinterpret_cast<u16x8*>(&HB[off]) = ldc8(H, off, f32);
  }
}

// ---------------- repack W1 hidden part -> bf16 transposed W1T[l][path*128+m][k] ----
// src: W1[l][512+k][m]  (k in [0,1024), m in [0,128)).  64-k-row tiles, 128 blocks.
__global__ void k_prep_w1t(const void* __restrict__ eaW1, const void* __restrict__ egW1,
                           const int* __restrict__ dflag, u16* __restrict__ W1T) {
  const bool f32 = dflag[0] != 0;
  __shared__ u16 sT[128*66];
  int l = blockIdx.x, path = blockIdx.y, kt = blockIdx.z;   // (4,2,16)
  int t = threadIdx.x;
  const void* W1 = path ? egW1 : eaW1;
  // read 64 k-rows x 128 m (coalesced over m), store transposed in LDS
  for (int rr = 0; rr < 64; rr += 2) {
    int r = rr + (t >> 7), m = t & 127;
    float v = ld1(W1, ((size_t)l*1536 + 512 + kt*64 + r)*MLPD + m, f32);
    sT[m*66 + r] = f2b(v);
  }
  __syncthreads();
  // write rows of W1T (coalesced over k)
  for (int mm = 0; mm < 128; mm += 4) {
    int m = mm + (t >> 6), kk = t & 63;
    W1T[((size_t)l*256 + path*128 + m)*1024 + kt*64 + kk] = sT[m*66 + kk];
  }
}

// ---------------- pack W2 -> bf16 NT W2M[l][o(512)][k(256)] ----------------
// k<128: W2a[l][k][o];  k>=128: -W2g[l][k-128][o]  (sign folded here).
__global__ void k_prep_w2m(const void* __restrict__ eaW2, const void* __restrict__ egW2,
                           const int* __restrict__ dflag, u16* __restrict__ W2M) {
  const bool f32 = dflag[0] != 0;
  __shared__ u16 sT[128*130];
  int l = blockIdx.x, path = blockIdx.y, ot = blockIdx.z;   // (4,2,4)
  int t = threadIdx.x;
  const void* W2 = path ? egW2 : eaW2;
  float sgn = path ? -1.0f : 1.0f;
  // read 128 m-rows x 128 o (coalesced over o), store transposed in LDS
  for (int rr = 0; rr < 128; rr += 2) {
    int r = rr + (t >> 7), o = t & 127;
    float v = ld1(W2, ((size_t)l*MLPD + r)*OUTD + ot*128 + o, f32);
    sT[o*130 + r] = f2b(sgn*v);
  }
  __syncthreads();
  // write rows of W2M (coalesced over m/k)
  for (int oo = 0; oo < 128; oo += 2) {
    int o = oo + (t >> 7), m = t & 127;
    W2M[((size_t)l*OUTD + ot*128 + o)*256 + path*128 + m] = sT[o*130 + m];
  }
}

// ---------------- base accumulation (x part of encoder layer 1) ----------------
__global__ void k_base_acc(const void* __restrict__ x, const void* __restrict__ eaW1,
                           const void* __restrict__ egW1, const int* __restrict__ dflag,
                           float* __restrict__ baseacc) {
  const bool f32 = dflag[0] != 0;
  int l = blockIdx.x, path = blockIdx.y, kc = blockIdx.z, m = threadIdx.x; // 128 thr
  const void* W1 = path ? egW1 : eaW1;
  float acc = 0.0f;
  int i0 = kc*128;
  for (int i = i0; i < i0 + 128; ++i)
    acc += ld1(x, i, f32) * ld1(W1, ((size_t)l*1536 + i)*MLPD + m, f32);
  atomicAdd(&baseacc[path*512 + l*MLPD + m], acc);
}

#define SWZ(row, ku) ((row)*64 + ((ku) ^ (((row)&7)<<3)))

// ---------------- MFMA k_z v3: Z = relu(base + b1 + HB @ W1T^T) ----------------
// 64x64 tile, 4 waves 2x2 (32x32 each), BK=64, dbuf, SWZ, 1 raw barrier/step.
__global__ __launch_bounds__(256) void k_z_mfma(
    const u16* __restrict__ HB, const u16* __restrict__ W1T,
    const void* __restrict__ eab1, const void* __restrict__ egb1,
    const float* __restrict__ baseacc, const int* __restrict__ dflag,
    u16* __restrict__ Z) {
  const bool f32 = dflag[0] != 0;
  __shared__ __align__(16) u16 sA[2][64*64];
  __shared__ __align__(16) u16 sB[2][64*64];
  int t = threadIdx.x;
  int row0 = blockIdx.x * 64;
  int n0   = blockIdx.y * 64;          // 0,64,128,192
  int l    = row0 >> 10;
  int wid = t >> 6, lane = t & 63;
  int waveM = wid >> 1, waveN = wid & 1;
  int quad = lane >> 4, lcol = lane & 15;

  f32x4 acc[2][2];
  const f32x4 zz = {0.0f,0.0f,0.0f,0.0f};
#pragma unroll
  for (int i = 0; i < 2; ++i)
#pragma unroll
    for (int j = 0; j < 2; ++j) acc[i][j] = zz;

  u16x8 ra[2], rb[2];
  auto loadk = [&](int k0) {
#pragma unroll
    for (int s = 0; s < 2; ++s) {
      int idx = s*256 + t, row = idx >> 3, ch = idx & 7;
      ra[s] = *reinterpret_cast<const u16x8*>(
          HB + (size_t)(row0 + row)*HID + k0 + ch*8);
      rb[s] = *reinterpret_cast<const u16x8*>(
          W1T + ((size_t)l*256 + n0 + row)*1024 + k0 + ch*8);
    }
  };
  auto stage = [&](int cb) {
#pragma unroll
    for (int s = 0; s < 2; ++s) {
      int idx = s*256 + t, row = idx >> 3, ch = idx & 7;
      *reinterpret_cast<u16x8*>(&sA[cb][SWZ(row, ch*8)]) = ra[s];
      *reinterpret_cast<u16x8*>(&sB[cb][SWZ(row, ch*8)]) = rb[s];
    }
  };

  int cur = 0;
  loadk(0);
  for (int k0 = 0; k0 < HID; k0 += 64) {
    stage(cur);
    asm volatile("s_waitcnt lgkmcnt(0)" ::: "memory");
    __builtin_amdgcn_s_barrier();
    if (k0 + 64 < HID) loadk(k0 + 64);
    __builtin_amdgcn_s_setprio(1);
#pragma unroll
    for (int kc = 0; kc < 2; ++kc) {
      bf16x8 af[2];
#pragma unroll
      for (int i = 0; i < 2; ++i) {
        int rl = waveM*32 + i*16 + lcol;
        af[i] = *reinterpret_cast<const bf16x8*>(&sA[cur][SWZ(rl, kc*32 + quad*8)]);
      }
#pragma unroll
      for (int j = 0; j < 2; ++j) {
        int jl = waveN*32 + j*16 + lcol;
        bf16x8 bf = *reinterpret_cast<const bf16x8*>(&sB[cur][SWZ(jl, kc*32 + quad*8)]);
#pragma unroll
        for (int i = 0; i < 2; ++i)
          acc[i][j] = __builtin_amdgcn_mfma_f32_16x16x32_bf16(af[i], bf, acc[i][j], 0, 0, 0);
      }
    }
    __builtin_amdgcn_s_setprio(0);
    cur ^= 1;
  }
  // epilogue: + base + b1, relu, store
#pragma unroll
  for (int j = 0; j < 2; ++j) {
    int nn = n0 + waveN*32 + j*16 + lcol;
    int path = nn >> 7, m = nn & 127;
    float bval = baseacc[path*512 + l*MLPD + m] +
                 ld1(path ? egb1 : eab1, l*MLPD + m, f32);
#pragma unroll
    for (int i = 0; i < 2; ++i)
#pragma unroll
      for (int g = 0; g < 4; ++g) {
        int r = row0 + waveM*32 + i*16 + quad*4 + g;
        float v = acc[i][j][g] + bval;
        Z[(size_t)r*256 + nn] = f2b(v > 0.0f ? v : 0.0f);
      }
  }
}

// ---------------- MFMA k_outm: OUT = Zb @ W2M^T + (b2a-b2g) ----------------
// M=4096, N=512, K=256. 128x64 tile, 4 waves (2Mx2J), BK=64, dbuf, SWZ.
__global__ __launch_bounds__(256) void k_outm(
    const u16* __restrict__ Zb, const u16* __restrict__ W2M,
    const void* __restrict__ eab2, const void* __restrict__ egb2,
    const int* __restrict__ dflag, u16* __restrict__ OUTT) {
  const bool f32 = dflag[0] != 0;
  __shared__ __align__(16) u16 sA[2][128*64];   // 32 KB
  __shared__ __align__(16) u16 sB[2][64*64];    // 16 KB
  int t = threadIdx.x;
  int row0 = blockIdx.x * 128;
  int n0   = blockIdx.y * 64;
  int l    = row0 >> 10;
  int wid = t >> 6, lane = t & 63;
  int waveM = wid & 1, waveJ = wid >> 1;
  int quad = lane >> 4, lcol = lane & 15;

  f32x4 acc[4][2];
  const f32x4 zz = {0.0f,0.0f,0.0f,0.0f};
#pragma unroll
  for (int i = 0; i < 4; ++i)
#pragma unroll
    for (int j = 0; j < 2; ++j) acc[i][j] = zz;

  u16x8 ra[4], rb[2];
  auto loadk = [&](int k0) {
#pragma unroll
    for (int s = 0; s < 4; ++s) {
      int idx = s*256 + t, row = idx >> 3, ch = idx & 7;
      ra[s] = *reinterpret_cast<const u16x8*>(
          Zb + (size_t)(row0 + row)*256 + k0 + ch*8);
    }
#pragma unroll
    for (int s = 0; s < 2; ++s) {
      int idx = s*256 + t, row = idx >> 3, ch = idx & 7;
      rb[s] = *reinterpret_cast<const u16x8*>(
          W2M + ((size_t)l*OUTD + n0 + row)*256 + k0 + ch*8);
    }
  };
  auto stage = [&](int cb) {
#pragma unroll
    for (int s = 0; s < 4; ++s) {
      int idx = s*256 + t, row = idx >> 3, ch = idx & 7;
      *reinterpret_cast<u16x8*>(&sA[cb][SWZ(row, ch*8)]) = ra[s];
    }
#pragma unroll
    for (int s = 0; s < 2; ++s) {
      int idx = s*256 + t, row = idx >> 3, ch = idx & 7;
      *reinterpret_cast<u16x8*>(&sB[cb][SWZ(row, ch*8)]) = rb[s];
    }
  };

  int cur = 0;
  loadk(0);
  for (int k0 = 0; k0 < 256; k0 += 64) {
    stage(cur);
    asm volatile("s_waitcnt lgkmcnt(0)" ::: "memory");
    __builtin_amdgcn_s_barrier();
    if (k0 + 64 < 256) loadk(k0 + 64);
    __builtin_amdgcn_s_setprio(1);
#pragma unroll
    for (int kc = 0; kc < 2; ++kc) {
      bf16x8 af[4];
#pragma unroll
      for (int i = 0; i < 4; ++i) {
        int rl = waveM*64 + i*16 + lcol;
        af[i] = *reinterpret_cast<const bf16x8*>(&sA[cur][SWZ(rl, kc*32 + quad*8)]);
      }
#pragma unroll
      for (int jj = 0; jj < 2; ++jj) {
        int jl = waveJ*32 + jj*16 + lcol;
        bf16x8 bf = *reinterpret_cast<const bf16x8*>(&sB[cur][SWZ(jl, kc*32 + quad*8)]);
#pragma unroll
        for (int i = 0; i < 4; ++i)
          acc[i][jj] = __builtin_amdgcn_mfma_f32_16x16x32_bf16(af[i], bf, acc[i][jj], 0, 0, 0);
      }
    }
    __builtin_amdgcn_s_setprio(0);
    cur ^= 1;
  }
  // epilogue: + bias diff, store bf16 into OUTT
#pragma unroll
  for (int jj = 0; jj < 2; ++jj) {
    int o = n0 + waveJ*32 + jj*16 + lcol;
    float bd = ld1(eab2, l*OUTD + o, f32) - ld1(egb2, l*OUTD + o, f32);
#pragma unroll
    for (int i = 0; i < 4; ++i)
#pragma unroll
      for (int g = 0; g < 4; ++g) {
        int r = row0 + waveM*64 + i*16 + quad*4 + g;
        OUTT[(size_t)r*KP + o] = f2b(acc[i][jj][g] + bd);
      }
  }
}

// tension -> OUTT col 512 (bf16); zero pad cols 513..543; tsum += sumsq(row)
__global__ void k_tension(u16* __restrict__ OUTT, float* __restrict__ tsum) {
  int row = blockIdx.x, t = threadIdx.x;
  u16* p = OUTT + (size_t)row*KP;
  float v0 = b2f(p[t]), v1 = b2f(p[t+256]);
  float s = v0*v0 + v1*v1;
#pragma unroll
  for (int off = 32; off > 0; off >>= 1) s += __shfl_down(s, off, 64);
  __shared__ float red[4];
  if ((t & 63) == 0) red[t >> 6] = s;
  __syncthreads();
  if (t == 0) {
    float tot = red[0] + red[1] + red[2] + red[3];
    p[512] = f2b(tot * (1.0f/512.0f));
    atomicAdd(tsum, tot);
  }
  if (t < 31) p[513 + t] = 0;
}

// ---------------- fused MFMA GRU v6: depth-2 prefetch, unified 25-step schedule ----
// Steps 0..8 = GEMM1 (gi, K=544, 64-wide with zero-padded tail); steps 9..24 =
// GEMM2 (gh, K=1024). Two NAMED reg sets (A/B) alternate: loads for step s+2
// are issued at step s -> each global load has ~2 compute phases to land.
// vmcnt never drains at a barrier (reg staging); lgkmcnt(0)+raw s_barrier only.
__global__ __launch_bounds__(256, 2) void k_gru_mfma(
    const u16* __restrict__ OUTT, const u16* __restrict__ HB,
    const u16* __restrict__ WihP, const u16* __restrict__ WhhP,
    const void* __restrict__ H,
    const float* __restrict__ bs_r, const float* __restrict__ bs_z,
    const float* __restrict__ bn_i, const float* __restrict__ bn_h,
    const int* __restrict__ dflag, void* __restrict__ outv) {
  const bool f32 = dflag[0] != 0;
  __shared__ __align__(16) u16 sA[2][128*64];     // 32 KB
  __shared__ __align__(16) u16 sB[2][3*64*64];    // 48 KB  (80 KB total, 2 blk/CU)
  int t = threadIdx.x;
  // XCD swizzle (512 blocks, 512%8==0 -> bijective): xg = XCD id.
  int bid = blockIdx.x;
  int xg = bid & 7, inner = bid >> 3;      // inner 0..63
  int l = xg & 3, jG = xg >> 2;
  int rbi = inner & 7, jbl = inner >> 3;   // 8 row-blocks, 8 j-blocks
  int row0 = (l*8 + rbi) * 128;
  int j0   = (jG*8 + jbl) * 64;
  int wid = t >> 6, lane = t & 63;
  int waveM = wid & 1, waveJ = wid >> 1;   // 2x2 waves over 128x64
  int quad = lane >> 4, lcol = lane & 15;

  f32x4 acc[4][4][2];   // band {r,z,i_n,h_n} x 4 m-frags x 2 j-frags
  const f32x4 zz = {0.0f,0.0f,0.0f,0.0f};
#pragma unroll
  for (int b = 0; b < 4; ++b)
#pragma unroll
    for (int i = 0; i < 4; ++i)
#pragma unroll
      for (int j = 0; j < 2; ++j) acc[b][i][j] = zz;

  // two named staging reg sets (depth-2 prefetch; static indexing per rule #20)
  u16x8 raA[4], rbA[6], raB[4], rbB[6];

  auto loadS = [&](u16x8 (&ra)[4], u16x8 (&rb)[6], int s) {
    if (s < 9) {                       // GEMM1: k0 = s*64, kw = KP - k0
      int k0 = s*64;
      int kw = KP - k0;                // 64 except s==8 (32)
#pragma unroll
      for (int q = 0; q < 4; ++q) {
        int idx = q*256 + t, row = idx >> 3, ch = idx & 7;
        if (ch*8 < kw)
          ra[q] = *reinterpret_cast<const u16x8*>(
              OUTT + (size_t)(row0 + row)*KP + k0 + ch*8);
        else { u16x8 z = {0,0,0,0,0,0,0,0}; ra[q] = z; }
      }
#pragma unroll
      for (int q = 0; q < 6; ++q) {
        int idx = q*256 + t, band = idx >> 9, rem = idx & 511;
        int row = rem >> 3, ch = rem & 7;
        if (ch*8 < kw)
          rb[q] = *reinterpret_cast<const u16x8*>(
              WihP + ((size_t)l*G3 + band*1024 + j0 + row)*KP + k0 + ch*8);
        else { u16x8 z = {0,0,0,0,0,0,0,0}; rb[q] = z; }
      }
    } else {                           // GEMM2: k0 = (s-9)*64
      int k0 = (s - 9)*64;
#pragma unroll
      for (int q = 0; q < 4; ++q) {
        int idx = q*256 + t, row = idx >> 3, ch = idx & 7;
        ra[q] = *reinterpret_cast<const u16x8*>(
            HB + (size_t)(row0 + row)*HID + k0 + ch*8);
      }
#pragma unroll
      for (int q = 0; q < 6; ++q) {
        int idx = q*256 + t, band = idx >> 9, rem = idx & 511;
        int row = rem >> 3, ch = rem & 7;
        rb[q] = *reinterpret_cast<const u16x8*>(
            WhhP + ((size_t)l*G3 + band*1024 + j0 + row)*HID + k0 + ch*8);
      }
    }
  };
  auto stage = [&](int cb, u16x8 (&ra)[4], u16x8 (&rb)[6]) {
#pragma unroll
    for (int q = 0; q < 4; ++q) {
      int idx = q*256 + t, row = idx >> 3, ch = idx & 7;
      *reinterpret_cast<u16x8*>(&sA[cb][SWZ(row, ch*8)]) = ra[q];
    }
#pragma unroll
    for (int q = 0; q < 6; ++q) {
      int idx = q*256 + t, band = idx >> 9, rem = idx & 511;
      int row = rem >> 3, ch = rem & 7;
      *reinterpret_cast<u16x8*>(&sB[cb][band*4096 + SWZ(row, ch*8)]) = rb[q];
    }
  };
  auto domfma = [&](int cb, bool g2) {
    __builtin_amdgcn_s_setprio(1);
#pragma unroll
    for (int kc = 0; kc < 2; ++kc) {
      bf16x8 af[4];
#pragma unroll
      for (int i = 0; i < 4; ++i) {
        int rl = waveM*64 + i*16 + lcol;
        af[i] = *reinterpret_cast<const bf16x8*>(&sA[cb][SWZ(rl, kc*32 + quad*8)]);
      }
#pragma unroll
      for (int b = 0; b < 3; ++b) {
        int ai = (g2 && b == 2) ? 3 : b;
#pragma unroll
        for (int jj = 0; jj < 2; ++jj) {
          int jl = waveJ*32 + jj*16 + lcol;
          bf16x8 bf = *reinterpret_cast<const bf16x8*>(
              &sB[cb][b*4096 + SWZ(jl, kc*32 + quad*8)]);
#pragma unroll
          for (int i = 0; i < 4; ++i)
            acc[ai][i][jj] = __builtin_amdgcn_mfma_f32_16x16x32_bf16(
                af[i], bf, acc[ai][i][jj], 0, 0, 0);
        }
      }
    }
    __builtin_amdgcn_s_setprio(0);
  };

  const int NS = 25;   // 9 (GEMM1) + 16 (GEMM2)
  int cur = 0;
  loadS(raA, rbA, 0);
  loadS(raB, rbB, 1);
  for (int s = 0; s < NS; s += 2) {
    // even step: set A
    stage(cur, raA, rbA);
    asm volatile("s_waitcnt lgkmcnt(0)" ::: "memory");
    __builtin_amdgcn_s_barrier();
    if (s + 2 < NS) loadS(raA, rbA, s + 2);
    domfma(cur, s >= 9);
    cur ^= 1;
    if (s + 1 < NS) {
      // odd step: set B
      stage(cur, raB, rbB);
      asm volatile("s_waitcnt lgkmcnt(0)" ::: "memory");
      __builtin_amdgcn_s_barrier();
      if (s + 3 < NS) loadS(raB, rbB, s + 3);
      domfma(cur, s + 1 >= 9);
      cur ^= 1;
    }
  }
  // ---- epilogue: gates -> new_h into d_out hh region (exact f32 h blend) ----
#pragma unroll
  for (int i = 0; i < 4; ++i)
#pragma unroll
    for (int jj = 0; jj < 2; ++jj) {
      int j = j0 + waveJ*32 + jj*16 + lcol;
      float br = bs_r[l*HID + j], bz = bs_z[l*HID + j];
      float bi = bn_i[l*HID + j], bh = bn_h[l*HID + j];
#pragma unroll
      for (int g = 0; g < 4; ++g) {
        int r = row0 + waveM*64 + i*16 + quad*4 + g;
        float rg = sigm(acc[0][i][jj][g] + br);
        float zg = sigm(acc[1][i][jj][g] + bz);
        float ng = tanhf(acc[2][i][jj][g] + bi + rg*(acc[3][i][jj][g] + bh));
        float hv = ld1(H, (size_t)r*HID + j, f32);
        st1(outv, 513 + (size_t)r*HID + j, (1.0f - zg)*ng + zg*hv, f32);
      }
    }
}

// ---------------- level means (split-C atomics; lm holds SUMS, scaled by consumers) ----
__global__ void k_lm_acc(const void* __restrict__ outv, const int* __restrict__ dflag,
                         float* __restrict__ lm) {
  const bool f32 = dflag[0] != 0;
  int l = blockIdx.x, cc = blockIdx.y, t = threadIdx.x;
  float s0=0.f, s1=0.f, s2=0.f, s3=0.f;
  for (int c = cc*16; c < cc*16 + 16; ++c) {
    size_t base = 513 + (size_t)(l*CPL + c)*HID;
    s0 += ld1(outv, base + t,       f32);
    s1 += ld1(outv, base + 256 + t, f32);
    s2 += ld1(outv, base + 512 + t, f32);
    s3 += ld1(outv, base + 768 + t, f32);
  }
  atomicAdd(&lm[l*HID + t],       s0);
  atomicAdd(&lm[l*HID + 256 + t], s1);
  atomicAdd(&lm[l*HID + 512 + t], s2);
  atomicAdd(&lm[l*HID + 768 + t], s3);
}

// ---------------- predictors (split-K atomics; SCL folds the 1/1024 mean) ----
__global__ void k_pz_acc(const float* __restrict__ lm, const void* __restrict__ pW1,
                         const int* __restrict__ dflag, float* __restrict__ pz) {
  const bool f32 = dflag[0] != 0;
  int lv = blockIdx.x, mb = blockIdx.y, kc = blockIdx.z;
  int m = mb*256 + threadIdx.x;
  float acc = 0.0f;
  int i0 = kc*32;
  const float* lmp = lm + (lv + 1)*HID;
  for (int i = i0; i < i0 + 32; ++i)
    acc += lmp[i] * ld1(pW1, ((size_t)lv*HID + i)*HID + m, f32);
  atomicAdd(&pz[lv*HID + m], acc * SCL);
}
// pz holds raw accumulated sums; bias+relu applied on read here (k_pzfin folded)
__global__ void k_pe_acc(const float* __restrict__ pz, const void* __restrict__ pb1,
                         const void* __restrict__ pW2,
                         const int* __restrict__ dflag, float* __restrict__ pe) {
  const bool f32 = dflag[0] != 0;
  int lv = blockIdx.x, ob = blockIdx.y, kc = blockIdx.z;
  int o = ob*256 + threadIdx.x;
  float acc = 0.0f;
  int m0 = kc*32;
  for (int m = m0; m < m0 + 32; ++m) {
    float v = pz[lv*HID + m] + ld1(pb1, lv*HID + m, f32);
    v = v > 0.0f ? v : 0.0f;
    acc += v * ld1(pW2, ((size_t)lv*HID + m)*HID + o, f32);
  }
  atomicAdd(&pe[lv*HID + o], acc);
}

// k_pefin folded in: pe_t = (pe_raw + pb2 - lm*SCL) * 0.05
__global__ void k_addc_gop(const float* __restrict__ lm, const float* __restrict__ pe,
                           const void* __restrict__ pb2, const int* __restrict__ dflag,
                           float* __restrict__ addc, float* __restrict__ gop) {
  const bool f32 = dflag[0] != 0;
  int j = blockIdx.x*256 + threadIdx.x;
  float pe0 = (pe[j]        + ld1(pb2, j,        f32) - lm[j]*SCL)        * 0.05f;
  float pe1 = (pe[1024 + j] + ld1(pb2, 1024 + j, f32) - lm[1024 + j]*SCL) * 0.05f;
  float pe2 = (pe[2048 + j] + ld1(pb2, 2048 + j, f32) - lm[2048 + j]*SCL) * 0.05f;
  float d0 = pe0, d1 = pe1 - 0.5f*pe0, d2 = pe2 - 0.5f*pe1, d3 = -0.5f*pe2;
  float l0 = lm[j]*SCL, l1 = lm[1024 + j]*SCL, l2 = lm[2048 + j]*SCL, l3 = lm[3072 + j]*SCL;
  addc[j]        = 0.2775f*l0 + d0;
  addc[1024 + j] = 0.2775f*l1 + d1;
  addc[2048 + j] = 0.2775f*l2 + d2;
  addc[3072 + j] = 0.2775f*l3 + d3;
  gop[j] = 0.25f*((l0 + d0) + (l1 + d1) + (l2 + d2) + (l3 + d3));
}

__global__ void k_comb_acc(const float* __restrict__ lm, const void* __restrict__ peiW,
                           const int* __restrict__ dflag, float* __restrict__ comb) {
  const bool f32 = dflag[0] != 0;
  int ob = blockIdx.x, kc = blockIdx.y;
  int o = ob*256 + threadIdx.x;
  float acc = 0.0f;
  int i0 = kc*128;
  for (int i = i0; i < i0 + 128; ++i)
    acc += lm[i] * ld1(peiW, (size_t)i*OUTD + o, f32);
  atomicAdd(&comb[o], acc * SCL);
}
__global__ void k_fin(const float* __restrict__ comb, const void* __restrict__ peib,
                      const float* __restrict__ tsum, const int* __restrict__ dflag,
                      void* __restrict__ outv) {
  const bool f32 = dflag[0] != 0;
  int o = blockIdx.x*256 + threadIdx.x;
  st1(outv, o, comb[o] + ld1(peib, o, f32), f32);
  if (o == 0) st1(outv, 512, tsum[0] * (1.0f/(4096.0f*512.0f)), f32);
}

__global__ void k_hh(void* __restrict__ outv, const float* __restrict__ addc,
                     const float* __restrict__ gop, const int* __restrict__ step,
                     const int* __restrict__ dflag) {
  const bool f32 = dflag[0] != 0;
  int row = blockIdx.x, t = threadIdx.x;
  int l = row >> 10, c = row & 1023;
  bool debate = (step[0] > 5) && (c < 256);
  size_t base = 513 + (size_t)row*HID;
#pragma unroll
  for (int k = 0; k < 4; ++k) {
    int j = t + k*256;
    float v = 0.7225f * ld1(outv, base + j, f32) + addc[l*HID + j];
    if (debate) v = 0.85f*v + 0.15f*gop[j];
    st1(outv, base + j, v, f32);
  }
}

extern "C" void kernel_launch(void* const* d_in, const int* in_sizes, int n_in,
                              void* d_out, int out_size, void* d_ws, size_t ws_size,
                              hipStream_t stream) {
  (void)in_sizes; (void)n_in; (void)out_size; (void)ws_size;
  const void* x    = d_in[0];
  const void* hid  = d_in[1];
  const void* eaW1 = d_in[2];
  const void* eab1 = d_in[3];
  const void* eaW2 = d_in[4];
  const void* eab2 = d_in[5];
  const void* egW1 = d_in[6];
  const void* egb1 = d_in[7];
  const void* egW2 = d_in[8];
  const void* egb2 = d_in[9];
  const void* gWih = d_in[10];
  const void* gWhh = d_in[11];
  const void* gbih = d_in[12];
  const void* gbhh = d_in[13];
  const void* pW1  = d_in[14];
  const void* pb1  = d_in[15];
  const void* pW2  = d_in[16];
  const void* pb2  = d_in[17];
  const void* peiW = d_in[18];
  const void* peib = d_in[19];
  const int*  step = (const int*)d_in[20];

  // ---- workspace layout (~54.6 MB) ----
  float* wsf = (float*)d_ws;
  float* tsum    = wsf + 0;       // 64
  float* baseacc = wsf + 64;      // 1024
  float* lm      = wsf + 1088;    // 4096
  float* pz      = wsf + 5184;    // 3072
  float* pe      = wsf + 8256;    // 3072
  float* comb    = wsf + 11328;   // 512 (+pad to 12288)
  int*   dflag   = (int*)(wsf + 12288);  // 64
  float* bs_r    = wsf + 12352;   // 4096
  float* bs_z    = wsf + 16448;   // 4096
  float* bn_i    = wsf + 20544;   // 4096
  float* bn_h    = wsf + 24640;   // 4096
  float* addc    = wsf + 28736;   // 4096
  float* gop     = wsf + 32832;   // 1024
  u16* Zb   = (u16*)(wsf + 33856);        // 4096*256
  u16* OUTT = Zb + (size_t)4096*256;      // 4096*544
  u16* WihP = OUTT + (size_t)4096*KP;     // 12288*544
  u16* HB   = WihP + (size_t)12288*KP;    // 4096*1024  (bf16 hiddens)
  u16* WhhP = HB   + (size_t)4096*1024;   // 12288*1024 (bf16 Whh)
  u16* W2M  = WhhP + (size_t)12288*1024;  // 4*512*256  (bf16 packed W2, 1 MB)
  // W1T (4*256*1024 u16 = 2.1 MB) overlays OUTT: dead once k_z finishes,
  // before k_outm writes OUTT.
  u16* W1T  = OUTT;

  k_detect   <<<dim3(1),        dim3(256), 0, stream>>>(x, dflag);
  k_prep     <<<dim3(64),       dim3(256), 0, stream>>>(wsf, gbih, gbhh, dflag,
                                                        bs_r, bs_z, bn_i, bn_h);
  k_prep_wih <<<dim3(12288),    dim3(256), 0, stream>>>(gWih, dflag, WihP);
  k_prep_cvt <<<dim3(8192),     dim3(256), 0, stream>>>(gWhh, hid, dflag, WhhP, HB);
  k_prep_w1t <<<dim3(4,2,16),   dim3(256), 0, stream>>>(eaW1, egW1, dflag, W1T);
  k_prep_w2m <<<dim3(4,2,4),    dim3(256), 0, stream>>>(eaW2, egW2, dflag, W2M);
  k_base_acc <<<dim3(4,2,4),    dim3(128), 0, stream>>>(x, eaW1, egW1, dflag, baseacc);
  k_z_mfma   <<<dim3(64,4),     dim3(256), 0, stream>>>(HB, W1T, eab1, egb1,
                                                        baseacc, dflag, Zb);
  k_outm     <<<dim3(32,8),     dim3(256), 0, stream>>>(Zb, W2M, eab2, egb2,
                                                        dflag, OUTT);
  k_tension  <<<dim3(4096),     dim3(256), 0, stream>>>(OUTT, tsum);
  k_gru_mfma <<<dim3(512),      dim3(256), 0, stream>>>(OUTT, HB, WihP, WhhP, hid,
                                                        bs_r, bs_z, bn_i, bn_h,
                                                        dflag, d_out);
  k_lm_acc   <<<dim3(4,64),     dim3(256), 0, stream>>>(d_out, dflag, lm);
  k_pz_acc   <<<dim3(3,4,32),   dim3(256), 0, stream>>>(lm, pW1, dflag, pz);
  k_pe_acc   <<<dim3(3,4,32),   dim3(256), 0, stream>>>(pz, pb1, pW2, dflag, pe);
  k_addc_gop <<<dim3(4),        dim3(256), 0, stream>>>(lm, pe, pb2, dflag, addc, gop);
  k_comb_acc <<<dim3(2,32),     dim3(256), 0, stream>>>(lm, peiW, dflag, comb);
  k_fin      <<<dim3(2),        dim3(256), 0, stream>>>(comb, peib, tsum, dflag, d_out);
  k_hh       <<<dim3(4096),     dim3(256), 0, stream>>>(d_out, addc, gop, step, dflag);
}

// Round 8
// 469.062 us; speedup vs baseline: 1.0183x; 1.0075x over previous
//
#include <hip/hip_runtime.h>
#include <math.h>

// Problem constants
#define L4   4
#define CPL  1024
#define HID  1024
#define IND  512
#define MLPD 128
#define OUTD 512
#define G3   3072
#define ROWS 4096   // L4*CPL
#define KP   544    // padded gi K: 512 OUT + 1 tension + 31 zeros
#define SCL  0.0009765625f   // 1/1024, exact pow2

typedef unsigned short u16;
typedef u16   u16x8  __attribute__((ext_vector_type(8)));
typedef short bf16x8 __attribute__((ext_vector_type(8)));
typedef float f32x4  __attribute__((ext_vector_type(4)));

__device__ __forceinline__ float b2f(u16 u) {
  return __uint_as_float(((unsigned int)u) << 16);
}
__device__ __forceinline__ u16 f2b(float f) {   // round-to-nearest-even
  unsigned int x = __float_as_uint(f);
  x += 0x7fffu + ((x >> 16) & 1u);
  return (u16)(x >> 16);
}
__device__ __forceinline__ float sigm(float v) { return 1.0f/(1.0f + expf(-v)); }

// ---- dual-dtype access helpers: f32 flag selects float32 vs bf16 layout ----
__device__ __forceinline__ float ld1(const void* p, size_t i, bool f32) {
  return f32 ? ((const float*)p)[i] : b2f(((const u16*)p)[i]);
}
__device__ __forceinline__ void st1(void* p, size_t i, float v, bool f32) {
  if (f32) ((float*)p)[i] = v; else ((u16*)p)[i] = f2b(v);
}
// load 8 elems -> bf16 bits (converting if fp32). i must be multiple of 8.
__device__ __forceinline__ u16x8 ldc8(const void* p, size_t i, bool f32) {
  u16x8 r;
  if (f32) {
    const float* q = (const float*)p + i;
    float4 v0 = *reinterpret_cast<const float4*>(q);
    float4 v1 = *reinterpret_cast<const float4*>(q + 4);
    r[0]=f2b(v0.x); r[1]=f2b(v0.y); r[2]=f2b(v0.z); r[3]=f2b(v0.w);
    r[4]=f2b(v1.x); r[5]=f2b(v1.y); r[6]=f2b(v1.z); r[7]=f2b(v1.w);
  } else {
    r = *reinterpret_cast<const u16x8*>((const u16*)p + i);
  }
  return r;
}

// ---------------- dtype detector ----------------
__global__ void k_detect(const void* __restrict__ x, int* __restrict__ flag) {
  int t = threadIdx.x;   // 256
  const u16* xu = (const u16*)x;
  unsigned u = xu[2*t];
  int e = (u >> 7) & 0xFF;
  int good = (e >= 96 && e <= 134) ? 1 : 0;
  __shared__ int cnt[256];
  cnt[t] = good;
  __syncthreads();
  for (int s = 128; s > 0; s >>= 1) { if (t < s) cnt[t] += cnt[t+s]; __syncthreads(); }
  if (t == 0) flag[0] = (cnt[0] < 200) ? 1 : 0;   // 1 = float32, 0 = bf16
}

// ---------------- prep: zero accumulators + bias sums ----------------
__global__ void k_prep(float* __restrict__ zf, const void* __restrict__ bih,
                       const void* __restrict__ bhh, const int* __restrict__ dflag,
                       float* __restrict__ bs_r, float* __restrict__ bs_z,
                       float* __restrict__ bn_i, float* __restrict__ bn_h) {
  const bool f32 = dflag[0] != 0;
  int b = blockIdx.x, t = threadIdx.x;
  if (b < 16) {
    int idx = b*256 + t;          // [0,4096)
    int l = idx >> 10, j = idx & 1023;
    bs_r[idx] = ld1(bih, l*G3 + j, f32)        + ld1(bhh, l*G3 + j, f32);
    bs_z[idx] = ld1(bih, l*G3 + 1024 + j, f32) + ld1(bhh, l*G3 + 1024 + j, f32);
    bn_i[idx] = ld1(bih, l*G3 + 2048 + j, f32);
    bn_h[idx] = ld1(bhh, l*G3 + 2048 + j, f32);
  } else {
    int idx = (b-16)*256 + t;     // [0,12288)
    zf[idx] = 0.0f;
  }
}

// ---------------- repack Wih -> bf16 [4][3072][544] (col 512 = tension wt) ----
__global__ void k_prep_wih(const void* __restrict__ Wih, const int* __restrict__ dflag,
                           u16* __restrict__ WihP) {
  const bool f32 = dflag[0] != 0;
  int row = blockIdx.x;            // 0..12287 == l*3072+g
  int t = threadIdx.x;
  size_t src = (size_t)row * 513;
  size_t dst = (size_t)row * KP;
  WihP[dst + t]       = f2b(ld1(Wih, src + t, f32));
  WihP[dst + 256 + t] = f2b(ld1(Wih, src + 256 + t, f32));
  if (t < 32) {
    float v = (t == 0) ? ld1(Wih, src + 512, f32) : 0.0f;
    WihP[dst + 512 + t] = f2b(v);
  }
}

// ---------------- convert Whh -> WhhP and hiddens -> HB (bf16), one launch ----
__global__ void k_prep_cvt(const void* __restrict__ Whh, const void* __restrict__ H,
                           const int* __restrict__ dflag,
                           u16* __restrict__ WhhP, u16* __restrict__ HB) {
  const bool f32 = dflag[0] != 0;
  int t = threadIdx.x;
  int b = blockIdx.x;                      // [0, 8192): 6144 Whh + 2048 HB
  int c8 = (t & 127) * 8;
  if (b < 6144) {
    int row = b*2 + (t >> 7);              // [0,12288)
    size_t off = (size_t)row * HID + c8;
    *reinterpret_cast<u16x8*>(&WhhP[off]) = ldc8(Whh, off, f32);
  } else {
    int row = (b - 6144)*2 + (t >> 7);     // [0,4096)
    size_t off = (size_t)row * HID + c8;
    *reinterpret_cast<u16x8*>(&HB[off]) = ldc8(H, off, f32);
  }
}

// ---------------- repack W1 hidden part -> bf16 transposed W1T[l][path*128+m][k] ----
// src: W1[l][512+k][m]  (k in [0,1024), m in [0,128)).  64-k-row tiles, 128 blocks.
__global__ void k_prep_w1t(const void* __restrict__ eaW1, const void* __restrict__ egW1,
                           const int* __restrict__ dflag, u16* __restrict__ W1T) {
  const bool f32 = dflag[0] != 0;
  __shared__ u16 sT[128*66];
  int l = blockIdx.x, path = blockIdx.y, kt = blockIdx.z;   // (4,2,16)
  int t = threadIdx.x;
  const void* W1 = path ? egW1 : eaW1;
  // read 64 k-rows x 128 m (coalesced over m), store transposed in LDS
  for (int rr = 0; rr < 64; rr += 2) {
    int r = rr + (t >> 7), m = t & 127;
    float v = ld1(W1, ((size_t)l*1536 + 512 + kt*64 + r)*MLPD + m, f32);
    sT[m*66 + r] = f2b(v);
  }
  __syncthreads();
  // write rows of W1T (coalesced over k)
  for (int mm = 0; mm < 128; mm += 4) {
    int m = mm + (t >> 6), kk = t & 63;
    W1T[((size_t)l*256 + path*128 + m)*1024 + kt*64 + kk] = sT[m*66 + kk];
  }
}

// ---------------- pack W2 -> bf16 NT W2M[l][o(512)][k(256)] ----------------
// k<128: W2a[l][k][o];  k>=128: -W2g[l][k-128][o]  (sign folded here).
__global__ void k_prep_w2m(const void* __restrict__ eaW2, const void* __restrict__ egW2,
                           const int* __restrict__ dflag, u16* __restrict__ W2M) {
  const bool f32 = dflag[0] != 0;
  __shared__ u16 sT[128*130];
  int l = blockIdx.x, path = blockIdx.y, ot = blockIdx.z;   // (4,2,4)
  int t = threadIdx.x;
  const void* W2 = path ? egW2 : eaW2;
  float sgn = path ? -1.0f : 1.0f;
  // read 128 m-rows x 128 o (coalesced over o), store transposed in LDS
  for (int rr = 0; rr < 128; rr += 2) {
    int r = rr + (t >> 7), o = t & 127;
    float v = ld1(W2, ((size_t)l*MLPD + r)*OUTD + ot*128 + o, f32);
    sT[o*130 + r] = f2b(sgn*v);
  }
  __syncthreads();
  // write rows of W2M (coalesced over m/k)
  for (int oo = 0; oo < 128; oo += 2) {
    int o = oo + (t >> 7), m = t & 127;
    W2M[((size_t)l*OUTD + ot*128 + o)*256 + path*128 + m] = sT[o*130 + m];
  }
}

// ---------------- base accumulation (x part of encoder layer 1) ----------------
__global__ void k_base_acc(const void* __restrict__ x, const void* __restrict__ eaW1,
                           const void* __restrict__ egW1, const int* __restrict__ dflag,
                           float* __restrict__ baseacc) {
  const bool f32 = dflag[0] != 0;
  int l = blockIdx.x, path = blockIdx.y, kc = blockIdx.z, m = threadIdx.x; // 128 thr
  const void* W1 = path ? egW1 : eaW1;
  float acc = 0.0f;
  int i0 = kc*128;
  for (int i = i0; i < i0 + 128; ++i)
    acc += ld1(x, i, f32) * ld1(W1, ((size_t)l*1536 + i)*MLPD + m, f32);
  atomicAdd(&baseacc[path*512 + l*MLPD + m], acc);
}

#define SWZ(row, ku) ((row)*64 + ((ku) ^ (((row)&7)<<3)))

// ---------------- MFMA k_z v3: Z = relu(base + b1 + HB @ W1T^T) ----------------
// 64x64 tile, 4 waves 2x2 (32x32 each), BK=64, dbuf, SWZ, 1 raw barrier/step.
__global__ __launch_bounds__(256) void k_z_mfma(
    const u16* __restrict__ HB, const u16* __restrict__ W1T,
    const void* __restrict__ eab1, const void* __restrict__ egb1,
    const float* __restrict__ baseacc, const int* __restrict__ dflag,
    u16* __restrict__ Z) {
  const bool f32 = dflag[0] != 0;
  __shared__ __align__(16) u16 sA[2][64*64];
  __shared__ __align__(16) u16 sB[2][64*64];
  int t = threadIdx.x;
  int row0 = blockIdx.x * 64;
  int n0   = blockIdx.y * 64;          // 0,64,128,192
  int l    = row0 >> 10;
  int wid = t >> 6, lane = t & 63;
  int waveM = wid >> 1, waveN = wid & 1;
  int quad = lane >> 4, lcol = lane & 15;

  f32x4 acc[2][2];
  const f32x4 zz = {0.0f,0.0f,0.0f,0.0f};
#pragma unroll
  for (int i = 0; i < 2; ++i)
#pragma unroll
    for (int j = 0; j < 2; ++j) acc[i][j] = zz;

  u16x8 ra[2], rb[2];
  auto loadk = [&](int k0) {
#pragma unroll
    for (int s = 0; s < 2; ++s) {
      int idx = s*256 + t, row = idx >> 3, ch = idx & 7;
      ra[s] = *reinterpret_cast<const u16x8*>(
          HB + (size_t)(row0 + row)*HID + k0 + ch*8);
      rb[s] = *reinterpret_cast<const u16x8*>(
          W1T + ((size_t)l*256 + n0 + row)*1024 + k0 + ch*8);
    }
  };
  auto stage = [&](int cb) {
#pragma unroll
    for (int s = 0; s < 2; ++s) {
      int idx = s*256 + t, row = idx >> 3, ch = idx & 7;
      *reinterpret_cast<u16x8*>(&sA[cb][SWZ(row, ch*8)]) = ra[s];
      *reinterpret_cast<u16x8*>(&sB[cb][SWZ(row, ch*8)]) = rb[s];
    }
  };

  int cur = 0;
  loadk(0);
  for (int k0 = 0; k0 < HID; k0 += 64) {
    stage(cur);
    asm volatile("s_waitcnt lgkmcnt(0)" ::: "memory");
    __builtin_amdgcn_s_barrier();
    if (k0 + 64 < HID) loadk(k0 + 64);
    __builtin_amdgcn_s_setprio(1);
#pragma unroll
    for (int kc = 0; kc < 2; ++kc) {
      bf16x8 af[2];
#pragma unroll
      for (int i = 0; i < 2; ++i) {
        int rl = waveM*32 + i*16 + lcol;
        af[i] = *reinterpret_cast<const bf16x8*>(&sA[cur][SWZ(rl, kc*32 + quad*8)]);
      }
#pragma unroll
      for (int j = 0; j < 2; ++j) {
        int jl = waveN*32 + j*16 + lcol;
        bf16x8 bf = *reinterpret_cast<const bf16x8*>(&sB[cur][SWZ(jl, kc*32 + quad*8)]);
#pragma unroll
        for (int i = 0; i < 2; ++i)
          acc[i][j] = __builtin_amdgcn_mfma_f32_16x16x32_bf16(af[i], bf, acc[i][j], 0, 0, 0);
      }
    }
    __builtin_amdgcn_s_setprio(0);
    cur ^= 1;
  }
  // epilogue: + base + b1, relu, store
#pragma unroll
  for (int j = 0; j < 2; ++j) {
    int nn = n0 + waveN*32 + j*16 + lcol;
    int path = nn >> 7, m = nn & 127;
    float bval = baseacc[path*512 + l*MLPD + m] +
                 ld1(path ? egb1 : eab1, l*MLPD + m, f32);
#pragma unroll
    for (int i = 0; i < 2; ++i)
#pragma unroll
      for (int g = 0; g < 4; ++g) {
        int r = row0 + waveM*32 + i*16 + quad*4 + g;
        float v = acc[i][j][g] + bval;
        Z[(size_t)r*256 + nn] = f2b(v > 0.0f ? v : 0.0f);
      }
  }
}

// ---------------- MFMA k_outm: OUT = Zb @ W2M^T + (b2a-b2g) ----------------
// M=4096, N=512, K=256. 128x64 tile, 4 waves (2Mx2J), BK=64, dbuf, SWZ.
__global__ __launch_bounds__(256) void k_outm(
    const u16* __restrict__ Zb, const u16* __restrict__ W2M,
    const void* __restrict__ eab2, const void* __restrict__ egb2,
    const int* __restrict__ dflag, u16* __restrict__ OUTT) {
  const bool f32 = dflag[0] != 0;
  __shared__ __align__(16) u16 sA[2][128*64];   // 32 KB
  __shared__ __align__(16) u16 sB[2][64*64];    // 16 KB
  int t = threadIdx.x;
  int row0 = blockIdx.x * 128;
  int n0   = blockIdx.y * 64;
  int l    = row0 >> 10;
  int wid = t >> 6, lane = t & 63;
  int waveM = wid & 1, waveJ = wid >> 1;
  int quad = lane >> 4, lcol = lane & 15;

  f32x4 acc[4][2];
  const f32x4 zz = {0.0f,0.0f,0.0f,0.0f};
#pragma unroll
  for (int i = 0; i < 4; ++i)
#pragma unroll
    for (int j = 0; j < 2; ++j) acc[i][j] = zz;

  u16x8 ra[4], rb[2];
  auto loadk = [&](int k0) {
#pragma unroll
    for (int s = 0; s < 4; ++s) {
      int idx = s*256 + t, row = idx >> 3, ch = idx & 7;
      ra[s] = *reinterpret_cast<const u16x8*>(
          Zb + (size_t)(row0 + row)*256 + k0 + ch*8);
    }
#pragma unroll
    for (int s = 0; s < 2; ++s) {
      int idx = s*256 + t, row = idx >> 3, ch = idx & 7;
      rb[s] = *reinterpret_cast<const u16x8*>(
          W2M + ((size_t)l*OUTD + n0 + row)*256 + k0 + ch*8);
    }
  };
  auto stage = [&](int cb) {
#pragma unroll
    for (int s = 0; s < 4; ++s) {
      int idx = s*256 + t, row = idx >> 3, ch = idx & 7;
      *reinterpret_cast<u16x8*>(&sA[cb][SWZ(row, ch*8)]) = ra[s];
    }
#pragma unroll
    for (int s = 0; s < 2; ++s) {
      int idx = s*256 + t, row = idx >> 3, ch = idx & 7;
      *reinterpret_cast<u16x8*>(&sB[cb][SWZ(row, ch*8)]) = rb[s];
    }
  };

  int cur = 0;
  loadk(0);
  for (int k0 = 0; k0 < 256; k0 += 64) {
    stage(cur);
    asm volatile("s_waitcnt lgkmcnt(0)" ::: "memory");
    __builtin_amdgcn_s_barrier();
    if (k0 + 64 < 256) loadk(k0 + 64);
    __builtin_amdgcn_s_setprio(1);
#pragma unroll
    for (int kc = 0; kc < 2; ++kc) {
      bf16x8 af[4];
#pragma unroll
      for (int i = 0; i < 4; ++i) {
        int rl = waveM*64 + i*16 + lcol;
        af[i] = *reinterpret_cast<const bf16x8*>(&sA[cur][SWZ(rl, kc*32 + quad*8)]);
      }
#pragma unroll
      for (int jj = 0; jj < 2; ++jj) {
        int jl = waveJ*32 + jj*16 + lcol;
        bf16x8 bf = *reinterpret_cast<const bf16x8*>(&sB[cur][SWZ(jl, kc*32 + quad*8)]);
#pragma unroll
        for (int i = 0; i < 4; ++i)
          acc[i][jj] = __builtin_amdgcn_mfma_f32_16x16x32_bf16(af[i], bf, acc[i][jj], 0, 0, 0);
      }
    }
    __builtin_amdgcn_s_setprio(0);
    cur ^= 1;
  }
  // epilogue: + bias diff, store bf16 into OUTT
#pragma unroll
  for (int jj = 0; jj < 2; ++jj) {
    int o = n0 + waveJ*32 + jj*16 + lcol;
    float bd = ld1(eab2, l*OUTD + o, f32) - ld1(egb2, l*OUTD + o, f32);
#pragma unroll
    for (int i = 0; i < 4; ++i)
#pragma unroll
      for (int g = 0; g < 4; ++g) {
        int r = row0 + waveM*64 + i*16 + quad*4 + g;
        OUTT[(size_t)r*KP + o] = f2b(acc[i][jj][g] + bd);
      }
  }
}

// tension -> OUTT col 512 (bf16); zero pad cols 513..543; tsum += sumsq(row)
__global__ void k_tension(u16* __restrict__ OUTT, float* __restrict__ tsum) {
  int row = blockIdx.x, t = threadIdx.x;
  u16* p = OUTT + (size_t)row*KP;
  float v0 = b2f(p[t]), v1 = b2f(p[t+256]);
  float s = v0*v0 + v1*v1;
#pragma unroll
  for (int off = 32; off > 0; off >>= 1) s += __shfl_down(s, off, 64);
  __shared__ float red[4];
  if ((t & 63) == 0) red[t >> 6] = s;
  __syncthreads();
  if (t == 0) {
    float tot = red[0] + red[1] + red[2] + red[3];
    p[512] = f2b(tot * (1.0f/512.0f));
    atomicAdd(tsum, tot);
  }
  if (t < 31) p[513 + t] = 0;
}

// ---------------- fused MFMA GRU v7: depth-2 prefetch, NAMED regs (no spill) ----
// 25-step unified schedule (9 GEMM1 + 16 GEMM2). Two named register sets SA_/SB_
// (20 u16x8 total) via token-pasting macros: no arrays, nothing address-taken,
// so the allocator keeps them in VGPRs (rule #20). Loads for step s+2 issued at
// step s; vmcnt never drains at a barrier.
#define GRULOAD(P, s) do {                                                     \
    if ((s) < 9) {                                                             \
      int k0 = (s)*64, kw = KP - k0;                                           \
      bool ok = ch8 < kw;                                                      \
      const u16* pA = OUTT + (size_t)row0*KP + k0 + ch8;                       \
      P##a0 = ok ? *(const u16x8*)(pA + (size_t)(arow     )*KP) : z8;          \
      P##a1 = ok ? *(const u16x8*)(pA + (size_t)(arow + 32)*KP) : z8;          \
      P##a2 = ok ? *(const u16x8*)(pA + (size_t)(arow + 64)*KP) : z8;          \
      P##a3 = ok ? *(const u16x8*)(pA + (size_t)(arow + 96)*KP) : z8;          \
      const u16* pB = WihP + ((size_t)l*G3 + j0)*KP + k0 + ch8;                \
      P##b0 = ok ? *(const u16x8*)(pB + (size_t)(   0 + arow     )*KP) : z8;   \
      P##b1 = ok ? *(const u16x8*)(pB + (size_t)(   0 + arow + 32)*KP) : z8;   \
      P##b2 = ok ? *(const u16x8*)(pB + (size_t)(1024 + arow     )*KP) : z8;   \
      P##b3 = ok ? *(const u16x8*)(pB + (size_t)(1024 + arow + 32)*KP) : z8;   \
      P##b4 = ok ? *(const u16x8*)(pB + (size_t)(2048 + arow     )*KP) : z8;   \
      P##b5 = ok ? *(const u16x8*)(pB + (size_t)(2048 + arow + 32)*KP) : z8;   \
    } else {                                                                   \
      int k0 = ((s) - 9)*64;                                                   \
      const u16* pA = HB + (size_t)row0*HID + k0 + ch8;                        \
      P##a0 = *(const u16x8*)(pA + (size_t)(arow     )*HID);                   \
      P##a1 = *(const u16x8*)(pA + (size_t)(arow + 32)*HID);                   \
      P##a2 = *(const u16x8*)(pA + (size_t)(arow + 64)*HID);                   \
      P##a3 = *(const u16x8*)(pA + (size_t)(arow + 96)*HID);                   \
      const u16* pB = WhhP + ((size_t)l*G3 + j0)*HID + k0 + ch8;               \
      P##b0 = *(const u16x8*)(pB + (size_t)(   0 + arow     )*HID);            \
      P##b1 = *(const u16x8*)(pB + (size_t)(   0 + arow + 32)*HID);            \
      P##b2 = *(const u16x8*)(pB + (size_t)(1024 + arow     )*HID);            \
      P##b3 = *(const u16x8*)(pB + (size_t)(1024 + arow + 32)*HID);            \
      P##b4 = *(const u16x8*)(pB + (size_t)(2048 + arow     )*HID);            \
      P##b5 = *(const u16x8*)(pB + (size_t)(2048 + arow + 32)*HID);            \
    }                                                                          \
  } while (0)

#define GRUSTAGE(P, cb) do {                                                   \
    *(u16x8*)&sA[cb][SWZ(arow,      ch8)] = P##a0;                             \
    *(u16x8*)&sA[cb][SWZ(arow + 32, ch8)] = P##a1;                             \
    *(u16x8*)&sA[cb][SWZ(arow + 64, ch8)] = P##a2;                             \
    *(u16x8*)&sA[cb][SWZ(arow + 96, ch8)] = P##a3;                             \
    *(u16x8*)&sB[cb][0*4096 + SWZ(arow,      ch8)] = P##b0;                    \
    *(u16x8*)&sB[cb][0*4096 + SWZ(arow + 32, ch8)] = P##b1;                    \
    *(u16x8*)&sB[cb][1*4096 + SWZ(arow,      ch8)] = P##b2;                    \
    *(u16x8*)&sB[cb][1*4096 + SWZ(arow + 32, ch8)] = P##b3;                    \
    *(u16x8*)&sB[cb][2*4096 + SWZ(arow,      ch8)] = P##b4;                    \
    *(u16x8*)&sB[cb][2*4096 + SWZ(arow + 32, ch8)] = P##b5;                    \
  } while (0)

__global__ __launch_bounds__(256, 2) void k_gru_mfma(
    const u16* __restrict__ OUTT, const u16* __restrict__ HB,
    const u16* __restrict__ WihP, const u16* __restrict__ WhhP,
    const void* __restrict__ H,
    const float* __restrict__ bs_r, const float* __restrict__ bs_z,
    const float* __restrict__ bn_i, const float* __restrict__ bn_h,
    const int* __restrict__ dflag, void* __restrict__ outv) {
  const bool f32 = dflag[0] != 0;
  __shared__ __align__(16) u16 sA[2][128*64];     // 32 KB
  __shared__ __align__(16) u16 sB[2][3*64*64];    // 48 KB  (80 KB total, 2 blk/CU)
  int t = threadIdx.x;
  // XCD swizzle (512 blocks, 512%8==0 -> bijective): xg = XCD id.
  int bid = blockIdx.x;
  int xg = bid & 7, inner = bid >> 3;      // inner 0..63
  int l = xg & 3, jG = xg >> 2;
  int rbi = inner & 7, jbl = inner >> 3;   // 8 row-blocks, 8 j-blocks
  int row0 = (l*8 + rbi) * 128;
  int j0   = (jG*8 + jbl) * 64;
  int wid = t >> 6, lane = t & 63;
  int waveM = wid & 1, waveJ = wid >> 1;   // 2x2 waves over 128x64
  int quad = lane >> 4, lcol = lane & 15;
  int arow = t >> 3, ch8 = (t & 7)*8;      // staging decomposition

  f32x4 acc[4][4][2];   // band {r,z,i_n,h_n} x 4 m-frags x 2 j-frags
  const f32x4 zz = {0.0f,0.0f,0.0f,0.0f};
#pragma unroll
  for (int b = 0; b < 4; ++b)
#pragma unroll
    for (int i = 0; i < 4; ++i)
#pragma unroll
      for (int j = 0; j < 2; ++j) acc[b][i][j] = zz;

  const u16x8 z8 = {0,0,0,0,0,0,0,0};
  // two named staging reg sets (depth-2 prefetch; NO arrays -> no scratch)
  u16x8 SA_a0, SA_a1, SA_a2, SA_a3, SA_b0, SA_b1, SA_b2, SA_b3, SA_b4, SA_b5;
  u16x8 SB_a0, SB_a1, SB_a2, SB_a3, SB_b0, SB_b1, SB_b2, SB_b3, SB_b4, SB_b5;

  auto domfma = [&](int cb, bool g2) {
    __builtin_amdgcn_s_setprio(1);
#pragma unroll
    for (int kc = 0; kc < 2; ++kc) {
      bf16x8 af[4];
#pragma unroll
      for (int i = 0; i < 4; ++i) {
        int rl = waveM*64 + i*16 + lcol;
        af[i] = *reinterpret_cast<const bf16x8*>(&sA[cb][SWZ(rl, kc*32 + quad*8)]);
      }
#pragma unroll
      for (int b = 0; b < 3; ++b) {
        int ai = (g2 && b == 2) ? 3 : b;
#pragma unroll
        for (int jj = 0; jj < 2; ++jj) {
          int jl = waveJ*32 + jj*16 + lcol;
          bf16x8 bf = *reinterpret_cast<const bf16x8*>(
              &sB[cb][b*4096 + SWZ(jl, kc*32 + quad*8)]);
#pragma unroll
          for (int i = 0; i < 4; ++i)
            acc[ai][i][jj] = __builtin_amdgcn_mfma_f32_16x16x32_bf16(
                af[i], bf, acc[ai][i][jj], 0, 0, 0);
        }
      }
    }
    __builtin_amdgcn_s_setprio(0);
  };

  const int NS = 25;   // 9 (GEMM1) + 16 (GEMM2)
  int cur = 0;
  GRULOAD(SA_, 0);
  GRULOAD(SB_, 1);
  for (int s = 0; s < NS; s += 2) {
    // even step: set SA_
    GRUSTAGE(SA_, cur);
    asm volatile("s_waitcnt lgkmcnt(0)" ::: "memory");
    __builtin_amdgcn_s_barrier();
    if (s + 2 < NS) GRULOAD(SA_, s + 2);
    domfma(cur, s >= 9);
    cur ^= 1;
    if (s + 1 < NS) {
      // odd step: set SB_
      GRUSTAGE(SB_, cur);
      asm volatile("s_waitcnt lgkmcnt(0)" ::: "memory");
      __builtin_amdgcn_s_barrier();
      if (s + 3 < NS) GRULOAD(SB_, s + 3);
      domfma(cur, s + 1 >= 9);
      cur ^= 1;
    }
  }
  // ---- epilogue: gates -> new_h into d_out hh region (exact f32 h blend) ----
#pragma unroll
  for (int i = 0; i < 4; ++i)
#pragma unroll
    for (int jj = 0; jj < 2; ++jj) {
      int j = j0 + waveJ*32 + jj*16 + lcol;
      float br = bs_r[l*HID + j], bz = bs_z[l*HID + j];
      float bi = bn_i[l*HID + j], bh = bn_h[l*HID + j];
#pragma unroll
      for (int g = 0; g < 4; ++g) {
        int r = row0 + waveM*64 + i*16 + quad*4 + g;
        float rg = sigm(acc[0][i][jj][g] + br);
        float zg = sigm(acc[1][i][jj][g] + bz);
        float ng = tanhf(acc[2][i][jj][g] + bi + rg*(acc[3][i][jj][g] + bh));
        float hv = ld1(H, (size_t)r*HID + j, f32);
        st1(outv, 513 + (size_t)r*HID + j, (1.0f - zg)*ng + zg*hv, f32);
      }
    }
}

// ---------------- level means (split-C atomics; lm holds SUMS, scaled by consumers) ----
__global__ void k_lm_acc(const void* __restrict__ outv, const int* __restrict__ dflag,
                         float* __restrict__ lm) {
  const bool f32 = dflag[0] != 0;
  int l = blockIdx.x, cc = blockIdx.y, t = threadIdx.x;
  float s0=0.f, s1=0.f, s2=0.f, s3=0.f;
  for (int c = cc*16; c < cc*16 + 16; ++c) {
    size_t base = 513 + (size_t)(l*CPL + c)*HID;
    s0 += ld1(outv, base + t,       f32);
    s1 += ld1(outv, base + 256 + t, f32);
    s2 += ld1(outv, base + 512 + t, f32);
    s3 += ld1(outv, base + 768 + t, f32);
  }
  atomicAdd(&lm[l*HID + t],       s0);
  atomicAdd(&lm[l*HID + 256 + t], s1);
  atomicAdd(&lm[l*HID + 512 + t], s2);
  atomicAdd(&lm[l*HID + 768 + t], s3);
}

// ---------------- predictors (split-K atomics; SCL folds the 1/1024 mean) ----
__global__ void k_pz_acc(const float* __restrict__ lm, const void* __restrict__ pW1,
                         const int* __restrict__ dflag, float* __restrict__ pz) {
  const bool f32 = dflag[0] != 0;
  int lv = blockIdx.x, mb = blockIdx.y, kc = blockIdx.z;
  int m = mb*256 + threadIdx.x;
  float acc = 0.0f;
  int i0 = kc*32;
  const float* lmp = lm + (lv + 1)*HID;
  for (int i = i0; i < i0 + 32; ++i)
    acc += lmp[i] * ld1(pW1, ((size_t)lv*HID + i)*HID + m, f32);
  atomicAdd(&pz[lv*HID + m], acc * SCL);
}
// pz holds raw accumulated sums; bias+relu applied on read here (k_pzfin folded)
__global__ void k_pe_acc(const float* __restrict__ pz, const void* __restrict__ pb1,
                         const void* __restrict__ pW2,
                         const int* __restrict__ dflag, float* __restrict__ pe) {
  const bool f32 = dflag[0] != 0;
  int lv = blockIdx.x, ob = blockIdx.y, kc = blockIdx.z;
  int o = ob*256 + threadIdx.x;
  float acc = 0.0f;
  int m0 = kc*32;
  for (int m = m0; m < m0 + 32; ++m) {
    float v = pz[lv*HID + m] + ld1(pb1, lv*HID + m, f32);
    v = v > 0.0f ? v : 0.0f;
    acc += v * ld1(pW2, ((size_t)lv*HID + m)*HID + o, f32);
  }
  atomicAdd(&pe[lv*HID + o], acc);
}

// k_pefin folded in: pe_t = (pe_raw + pb2 - lm*SCL) * 0.05
__global__ void k_addc_gop(const float* __restrict__ lm, const float* __restrict__ pe,
                           const void* __restrict__ pb2, const int* __restrict__ dflag,
                           float* __restrict__ addc, float* __restrict__ gop) {
  const bool f32 = dflag[0] != 0;
  int j = blockIdx.x*256 + threadIdx.x;
  float pe0 = (pe[j]        + ld1(pb2, j,        f32) - lm[j]*SCL)        * 0.05f;
  float pe1 = (pe[1024 + j] + ld1(pb2, 1024 + j, f32) - lm[1024 + j]*SCL) * 0.05f;
  float pe2 = (pe[2048 + j] + ld1(pb2, 2048 + j, f32) - lm[2048 + j]*SCL) * 0.05f;
  float d0 = pe0, d1 = pe1 - 0.5f*pe0, d2 = pe2 - 0.5f*pe1, d3 = -0.5f*pe2;
  float l0 = lm[j]*SCL, l1 = lm[1024 + j]*SCL, l2 = lm[2048 + j]*SCL, l3 = lm[3072 + j]*SCL;
  addc[j]        = 0.2775f*l0 + d0;
  addc[1024 + j] = 0.2775f*l1 + d1;
  addc[2048 + j] = 0.2775f*l2 + d2;
  addc[3072 + j] = 0.2775f*l3 + d3;
  gop[j] = 0.25f*((l0 + d0) + (l1 + d1) + (l2 + d2) + (l3 + d3));
}

__global__ void k_comb_acc(const float* __restrict__ lm, const void* __restrict__ peiW,
                           const int* __restrict__ dflag, float* __restrict__ comb) {
  const bool f32 = dflag[0] != 0;
  int ob = blockIdx.x, kc = blockIdx.y;
  int o = ob*256 + threadIdx.x;
  float acc = 0.0f;
  int i0 = kc*128;
  for (int i = i0; i < i0 + 128; ++i)
    acc += lm[i] * ld1(peiW, (size_t)i*OUTD + o, f32);
  atomicAdd(&comb[o], acc * SCL);
}
__global__ void k_fin(const float* __restrict__ comb, const void* __restrict__ peib,
                      const float* __restrict__ tsum, const int* __restrict__ dflag,
                      void* __restrict__ outv) {
  const bool f32 = dflag[0] != 0;
  int o = blockIdx.x*256 + threadIdx.x;
  st1(outv, o, comb[o] + ld1(peib, o, f32), f32);
  if (o == 0) st1(outv, 512, tsum[0] * (1.0f/(4096.0f*512.0f)), f32);
}

__global__ void k_hh(void* __restrict__ outv, const float* __restrict__ addc,
                     const float* __restrict__ gop, const int* __restrict__ step,
                     const int* __restrict__ dflag) {
  const bool f32 = dflag[0] != 0;
  int row = blockIdx.x, t = threadIdx.x;
  int l = row >> 10, c = row & 1023;
  bool debate = (step[0] > 5) && (c < 256);
  size_t base = 513 + (size_t)row*HID;
#pragma unroll
  for (int k = 0; k < 4; ++k) {
    int j = t + k*256;
    float v = 0.7225f * ld1(outv, base + j, f32) + addc[l*HID + j];
    if (debate) v = 0.85f*v + 0.15f*gop[j];
    st1(outv, base + j, v, f32);
  }
}

extern "C" void kernel_launch(void* const* d_in, const int* in_sizes, int n_in,
                              void* d_out, int out_size, void* d_ws, size_t ws_size,
                              hipStream_t stream) {
  (void)in_sizes; (void)n_in; (void)out_size; (void)ws_size;
  const void* x    = d_in[0];
  const void* hid  = d_in[1];
  const void* eaW1 = d_in[2];
  const void* eab1 = d_in[3];
  const void* eaW2 = d_in[4];
  const void* eab2 = d_in[5];
  const void* egW1 = d_in[6];
  const void* egb1 = d_in[7];
  const void* egW2 = d_in[8];
  const void* egb2 = d_in[9];
  const void* gWih = d_in[10];
  const void* gWhh = d_in[11];
  const void* gbih = d_in[12];
  const void* gbhh = d_in[13];
  const void* pW1  = d_in[14];
  const void* pb1  = d_in[15];
  const void* pW2  = d_in[16];
  const void* pb2  = d_in[17];
  const void* peiW = d_in[18];
  const void* peib = d_in[19];
  const int*  step = (const int*)d_in[20];

  // ---- workspace layout (~54.6 MB) ----
  float* wsf = (float*)d_ws;
  float* tsum    = wsf + 0;       // 64
  float* baseacc = wsf + 64;      // 1024
  float* lm      = wsf + 1088;    // 4096
  float* pz      = wsf + 5184;    // 3072
  float* pe      = wsf + 8256;    // 3072
  float* comb    = wsf + 11328;   // 512 (+pad to 12288)
  int*   dflag   = (int*)(wsf + 12288);  // 64
  float* bs_r    = wsf + 12352;   // 4096
  float* bs_z    = wsf + 16448;   // 4096
  float* bn_i    = wsf + 20544;   // 4096
  float* bn_h    = wsf + 24640;   // 4096
  float* addc    = wsf + 28736;   // 4096
  float* gop     = wsf + 32832;   // 1024
  u16* Zb   = (u16*)(wsf + 33856);        // 4096*256
  u16* OUTT = Zb + (size_t)4096*256;      // 4096*544
  u16* WihP = OUTT + (size_t)4096*KP;     // 12288*544
  u16* HB   = WihP + (size_t)12288*KP;    // 4096*1024  (bf16 hiddens)
  u16* WhhP = HB   + (size_t)4096*1024;   // 12288*1024 (bf16 Whh)
  u16* W2M  = WhhP + (size_t)12288*1024;  // 4*512*256  (bf16 packed W2, 1 MB)
  // W1T (4*256*1024 u16 = 2.1 MB) overlays OUTT: dead once k_z finishes,
  // before k_outm writes OUTT.
  u16* W1T  = OUTT;

  k_detect   <<<dim3(1),        dim3(256), 0, stream>>>(x, dflag);
  k_prep     <<<dim3(64),       dim3(256), 0, stream>>>(wsf, gbih, gbhh, dflag,
                                                        bs_r, bs_z, bn_i, bn_h);
  k_prep_wih <<<dim3(12288),    dim3(256), 0, stream>>>(gWih, dflag, WihP);
  k_prep_cvt <<<dim3(8192),     dim3(256), 0, stream>>>(gWhh, hid, dflag, WhhP, HB);
  k_prep_w1t <<<dim3(4,2,16),   dim3(256), 0, stream>>>(eaW1, egW1, dflag, W1T);
  k_prep_w2m <<<dim3(4,2,4),    dim3(256), 0, stream>>>(eaW2, egW2, dflag, W2M);
  k_base_acc <<<dim3(4,2,4),    dim3(128), 0, stream>>>(x, eaW1, egW1, dflag, baseacc);
  k_z_mfma   <<<dim3(64,4),     dim3(256), 0, stream>>>(HB, W1T, eab1, egb1,
                                                        baseacc, dflag, Zb);
  k_outm     <<<dim3(32,8),     dim3(256), 0, stream>>>(Zb, W2M, eab2, egb2,
                                                        dflag, OUTT);
  k_tension  <<<dim3(4096),     dim3(256), 0, stream>>>(OUTT, tsum);
  k_gru_mfma <<<dim3(512),      dim3(256), 0, stream>>>(OUTT, HB, WihP, WhhP, hid,
                                                        bs_r, bs_z, bn_i, bn_h,
                                                        dflag, d_out);
  k_lm_acc   <<<dim3(4,64),     dim3(256), 0, stream>>>(d_out, dflag, lm);
  k_pz_acc   <<<dim3(3,4,32),   dim3(256), 0, stream>>>(lm, pW1, dflag, pz);
  k_pe_acc   <<<dim3(3,4,32),   dim3(256), 0, stream>>>(pz, pb1, pW2, dflag, pe);
  k_addc_gop <<<dim3(4),        dim3(256), 0, stream>>>(lm, pe, pb2, dflag, addc, gop);
  k_comb_acc <<<dim3(2,32),     dim3(256), 0, stream>>>(lm, peiW, dflag, comb);
  k_fin      <<<dim3(2),        dim3(256), 0, stream>>>(comb, peib, tsum, dflag, d_out);
  k_hh       <<<dim3(4096),     dim3(256), 0, stream>>>(d_out, addc, gop, step, dflag);
}

// Round 9
// 467.715 us; speedup vs baseline: 1.0213x; 1.0029x over previous
//
#include <hip/hip_runtime.h>
#include <math.h>

// Problem constants
#define L4   4
#define CPL  1024
#define HID  1024
#define IND  512
#define MLPD 128
#define OUTD 512
#define G3   3072
#define ROWS 4096   // L4*CPL
#define KP   544    // padded gi K: 512 OUT + 1 tension + 31 zeros
#define SCL  0.0009765625f   // 1/1024, exact pow2

typedef unsigned short u16;
typedef u16   u16x8  __attribute__((ext_vector_type(8)));
typedef short bf16x8 __attribute__((ext_vector_type(8)));
typedef float f32x4  __attribute__((ext_vector_type(4)));

// address-space-typed pointers for global_load_lds
typedef __attribute__((address_space(3))) unsigned int lu32;
typedef const __attribute__((address_space(1))) unsigned int gu32;

__device__ __forceinline__ float b2f(u16 u) {
  return __uint_as_float(((unsigned int)u) << 16);
}
__device__ __forceinline__ u16 f2b(float f) {   // round-to-nearest-even
  unsigned int x = __float_as_uint(f);
  x += 0x7fffu + ((x >> 16) & 1u);
  return (u16)(x >> 16);
}
__device__ __forceinline__ float sigm(float v) { return 1.0f/(1.0f + expf(-v)); }

// ---- dual-dtype access helpers: f32 flag selects float32 vs bf16 layout ----
__device__ __forceinline__ float ld1(const void* p, size_t i, bool f32) {
  return f32 ? ((const float*)p)[i] : b2f(((const u16*)p)[i]);
}
__device__ __forceinline__ void st1(void* p, size_t i, float v, bool f32) {
  if (f32) ((float*)p)[i] = v; else ((u16*)p)[i] = f2b(v);
}
// load 8 elems -> bf16 bits (converting if fp32). i must be multiple of 8.
__device__ __forceinline__ u16x8 ldc8(const void* p, size_t i, bool f32) {
  u16x8 r;
  if (f32) {
    const float* q = (const float*)p + i;
    float4 v0 = *reinterpret_cast<const float4*>(q);
    float4 v1 = *reinterpret_cast<const float4*>(q + 4);
    r[0]=f2b(v0.x); r[1]=f2b(v0.y); r[2]=f2b(v0.z); r[3]=f2b(v0.w);
    r[4]=f2b(v1.x); r[5]=f2b(v1.y); r[6]=f2b(v1.z); r[7]=f2b(v1.w);
  } else {
    r = *reinterpret_cast<const u16x8*>((const u16*)p + i);
  }
  return r;
}

// ---------------- dtype detector ----------------
__global__ void k_detect(const void* __restrict__ x, int* __restrict__ flag) {
  int t = threadIdx.x;   // 256
  const u16* xu = (const u16*)x;
  unsigned u = xu[2*t];
  int e = (u >> 7) & 0xFF;
  int good = (e >= 96 && e <= 134) ? 1 : 0;
  __shared__ int cnt[256];
  cnt[t] = good;
  __syncthreads();
  for (int s = 128; s > 0; s >>= 1) { if (t < s) cnt[t] += cnt[t+s]; __syncthreads(); }
  if (t == 0) flag[0] = (cnt[0] < 200) ? 1 : 0;   // 1 = float32, 0 = bf16
}

// ---------------- prep: zero accumulators + bias sums ----------------
__global__ void k_prep(float* __restrict__ zf, const void* __restrict__ bih,
                       const void* __restrict__ bhh, const int* __restrict__ dflag,
                       float* __restrict__ bs_r, float* __restrict__ bs_z,
                       float* __restrict__ bn_i, float* __restrict__ bn_h) {
  const bool f32 = dflag[0] != 0;
  int b = blockIdx.x, t = threadIdx.x;
  if (b < 16) {
    int idx = b*256 + t;          // [0,4096)
    int l = idx >> 10, j = idx & 1023;
    bs_r[idx] = ld1(bih, l*G3 + j, f32)        + ld1(bhh, l*G3 + j, f32);
    bs_z[idx] = ld1(bih, l*G3 + 1024 + j, f32) + ld1(bhh, l*G3 + 1024 + j, f32);
    bn_i[idx] = ld1(bih, l*G3 + 2048 + j, f32);
    bn_h[idx] = ld1(bhh, l*G3 + 2048 + j, f32);
  } else {
    int idx = (b-16)*256 + t;     // [0,12288)
    zf[idx] = 0.0f;
  }
}

// ---------------- repack Wih -> bf16 [4][3072][544] (col 512 = tension wt) ----
__global__ void k_prep_wih(const void* __restrict__ Wih, const int* __restrict__ dflag,
                           u16* __restrict__ WihP) {
  const bool f32 = dflag[0] != 0;
  int row = blockIdx.x;            // 0..12287 == l*3072+g
  int t = threadIdx.x;
  size_t src = (size_t)row * 513;
  size_t dst = (size_t)row * KP;
  WihP[dst + t]       = f2b(ld1(Wih, src + t, f32));
  WihP[dst + 256 + t] = f2b(ld1(Wih, src + 256 + t, f32));
  if (t < 32) {
    float v = (t == 0) ? ld1(Wih, src + 512, f32) : 0.0f;
    WihP[dst + 512 + t] = f2b(v);
  }
}

// ---------------- convert Whh -> WhhP and hiddens -> HB (bf16), one launch ----
__global__ void k_prep_cvt(const void* __restrict__ Whh, const void* __restrict__ H,
                           const int* __restrict__ dflag,
                           u16* __restrict__ WhhP, u16* __restrict__ HB) {
  const bool f32 = dflag[0] != 0;
  int t = threadIdx.x;
  int b = blockIdx.x;                      // [0, 8192): 6144 Whh + 2048 HB
  int c8 = (t & 127) * 8;
  if (b < 6144) {
    int row = b*2 + (t >> 7);              // [0,12288)
    size_t off = (size_t)row * HID + c8;
    *reinterpret_cast<u16x8*>(&WhhP[off]) = ldc8(Whh, off, f32);
  } else {
    int row = (b - 6144)*2 + (t >> 7);     // [0,4096)
    size_t off = (size_t)row * HID + c8;
    *reinterpret_cast<u16x8*>(&HB[off]) = ldc8(H, off, f32);
  }
}

// ---------------- repack W1 hidden part -> bf16 transposed W1T[l][path*128+m][k] ----
// src: W1[l][512+k][m]  (k in [0,1024), m in [0,128)).  64-k-row tiles, 128 blocks.
__global__ void k_prep_w1t(const void* __restrict__ eaW1, const void* __restrict__ egW1,
                           const int* __restrict__ dflag, u16* __restrict__ W1T) {
  const bool f32 = dflag[0] != 0;
  __shared__ u16 sT[128*66];
  int l = blockIdx.x, path = blockIdx.y, kt = blockIdx.z;   // (4,2,16)
  int t = threadIdx.x;
  const void* W1 = path ? egW1 : eaW1;
  // read 64 k-rows x 128 m (coalesced over m), store transposed in LDS
  for (int rr = 0; rr < 64; rr += 2) {
    int r = rr + (t >> 7), m = t & 127;
    float v = ld1(W1, ((size_t)l*1536 + 512 + kt*64 + r)*MLPD + m, f32);
    sT[m*66 + r] = f2b(v);
  }
  __syncthreads();
  // write rows of W1T (coalesced over k)
  for (int mm = 0; mm < 128; mm += 4) {
    int m = mm + (t >> 6), kk = t & 63;
    W1T[((size_t)l*256 + path*128 + m)*1024 + kt*64 + kk] = sT[m*66 + kk];
  }
}

// ---------------- pack W2 -> bf16 NT W2M[l][o(512)][k(256)] ----------------
// k<128: W2a[l][k][o];  k>=128: -W2g[l][k-128][o]  (sign folded here).
__global__ void k_prep_w2m(const void* __restrict__ eaW2, const void* __restrict__ egW2,
                           const int* __restrict__ dflag, u16* __restrict__ W2M) {
  const bool f32 = dflag[0] != 0;
  __shared__ u16 sT[128*130];
  int l = blockIdx.x, path = blockIdx.y, ot = blockIdx.z;   // (4,2,4)
  int t = threadIdx.x;
  const void* W2 = path ? egW2 : eaW2;
  float sgn = path ? -1.0f : 1.0f;
  // read 128 m-rows x 128 o (coalesced over o), store transposed in LDS
  for (int rr = 0; rr < 128; rr += 2) {
    int r = rr + (t >> 7), o = t & 127;
    float v = ld1(W2, ((size_t)l*MLPD + r)*OUTD + ot*128 + o, f32);
    sT[o*130 + r] = f2b(sgn*v);
  }
  __syncthreads();
  // write rows of W2M (coalesced over m/k)
  for (int oo = 0; oo < 128; oo += 2) {
    int o = oo + (t >> 7), m = t & 127;
    W2M[((size_t)l*OUTD + ot*128 + o)*256 + path*128 + m] = sT[o*130 + m];
  }
}

// ---------------- base accumulation (x part of encoder layer 1) ----------------
__global__ void k_base_acc(const void* __restrict__ x, const void* __restrict__ eaW1,
                           const void* __restrict__ egW1, const int* __restrict__ dflag,
                           float* __restrict__ baseacc) {
  const bool f32 = dflag[0] != 0;
  int l = blockIdx.x, path = blockIdx.y, kc = blockIdx.z, m = threadIdx.x; // 128 thr
  const void* W1 = path ? egW1 : eaW1;
  float acc = 0.0f;
  int i0 = kc*128;
  for (int i = i0; i < i0 + 128; ++i)
    acc += ld1(x, i, f32) * ld1(W1, ((size_t)l*1536 + i)*MLPD + m, f32);
  atomicAdd(&baseacc[path*512 + l*MLPD + m], acc);
}

#define SWZ(row, ku) ((row)*64 + ((ku) ^ (((row)&7)<<3)))

// ---------------- MFMA k_z v3: Z = relu(base + b1 + HB @ W1T^T) ----------------
// 64x64 tile, 4 waves 2x2 (32x32 each), BK=64, dbuf, SWZ, 1 raw barrier/step.
__global__ __launch_bounds__(256) void k_z_mfma(
    const u16* __restrict__ HB, const u16* __restrict__ W1T,
    const void* __restrict__ eab1, const void* __restrict__ egb1,
    const float* __restrict__ baseacc, const int* __restrict__ dflag,
    u16* __restrict__ Z) {
  const bool f32 = dflag[0] != 0;
  __shared__ __align__(16) u16 sA[2][64*64];
  __shared__ __align__(16) u16 sB[2][64*64];
  int t = threadIdx.x;
  int row0 = blockIdx.x * 64;
  int n0   = blockIdx.y * 64;          // 0,64,128,192
  int l    = row0 >> 10;
  int wid = t >> 6, lane = t & 63;
  int waveM = wid >> 1, waveN = wid & 1;
  int quad = lane >> 4, lcol = lane & 15;

  f32x4 acc[2][2];
  const f32x4 zz = {0.0f,0.0f,0.0f,0.0f};
#pragma unroll
  for (int i = 0; i < 2; ++i)
#pragma unroll
    for (int j = 0; j < 2; ++j) acc[i][j] = zz;

  u16x8 ra[2], rb[2];
  auto loadk = [&](int k0) {
#pragma unroll
    for (int s = 0; s < 2; ++s) {
      int idx = s*256 + t, row = idx >> 3, ch = idx & 7;
      ra[s] = *reinterpret_cast<const u16x8*>(
          HB + (size_t)(row0 + row)*HID + k0 + ch*8);
      rb[s] = *reinterpret_cast<const u16x8*>(
          W1T + ((size_t)l*256 + n0 + row)*1024 + k0 + ch*8);
    }
  };
  auto stage = [&](int cb) {
#pragma unroll
    for (int s = 0; s < 2; ++s) {
      int idx = s*256 + t, row = idx >> 3, ch = idx & 7;
      *reinterpret_cast<u16x8*>(&sA[cb][SWZ(row, ch*8)]) = ra[s];
      *reinterpret_cast<u16x8*>(&sB[cb][SWZ(row, ch*8)]) = rb[s];
    }
  };

  int cur = 0;
  loadk(0);
  for (int k0 = 0; k0 < HID; k0 += 64) {
    stage(cur);
    asm volatile("s_waitcnt lgkmcnt(0)" ::: "memory");
    __builtin_amdgcn_s_barrier();
    if (k0 + 64 < HID) loadk(k0 + 64);
    __builtin_amdgcn_s_setprio(1);
#pragma unroll
    for (int kc = 0; kc < 2; ++kc) {
      bf16x8 af[2];
#pragma unroll
      for (int i = 0; i < 2; ++i) {
        int rl = waveM*32 + i*16 + lcol;
        af[i] = *reinterpret_cast<const bf16x8*>(&sA[cur][SWZ(rl, kc*32 + quad*8)]);
      }
#pragma unroll
      for (int j = 0; j < 2; ++j) {
        int jl = waveN*32 + j*16 + lcol;
        bf16x8 bf = *reinterpret_cast<const bf16x8*>(&sB[cur][SWZ(jl, kc*32 + quad*8)]);
#pragma unroll
        for (int i = 0; i < 2; ++i)
          acc[i][j] = __builtin_amdgcn_mfma_f32_16x16x32_bf16(af[i], bf, acc[i][j], 0, 0, 0);
      }
    }
    __builtin_amdgcn_s_setprio(0);
    cur ^= 1;
  }
  // epilogue: + base + b1, relu, store
#pragma unroll
  for (int j = 0; j < 2; ++j) {
    int nn = n0 + waveN*32 + j*16 + lcol;
    int path = nn >> 7, m = nn & 127;
    float bval = baseacc[path*512 + l*MLPD + m] +
                 ld1(path ? egb1 : eab1, l*MLPD + m, f32);
#pragma unroll
    for (int i = 0; i < 2; ++i)
#pragma unroll
      for (int g = 0; g < 4; ++g) {
        int r = row0 + waveM*32 + i*16 + quad*4 + g;
        float v = acc[i][j][g] + bval;
        Z[(size_t)r*256 + nn] = f2b(v > 0.0f ? v : 0.0f);
      }
  }
}

// ---------------- MFMA k_outm: OUT = Zb @ W2M^T + (b2a-b2g) ----------------
// M=4096, N=512, K=256. 128x64 tile, 4 waves (2Mx2J), BK=64, dbuf, SWZ.
__global__ __launch_bounds__(256) void k_outm(
    const u16* __restrict__ Zb, const u16* __restrict__ W2M,
    const void* __restrict__ eab2, const void* __restrict__ egb2,
    const int* __restrict__ dflag, u16* __restrict__ OUTT) {
  const bool f32 = dflag[0] != 0;
  __shared__ __align__(16) u16 sA[2][128*64];   // 32 KB
  __shared__ __align__(16) u16 sB[2][64*64];    // 16 KB
  int t = threadIdx.x;
  int row0 = blockIdx.x * 128;
  int n0   = blockIdx.y * 64;
  int l    = row0 >> 10;
  int wid = t >> 6, lane = t & 63;
  int waveM = wid & 1, waveJ = wid >> 1;
  int quad = lane >> 4, lcol = lane & 15;

  f32x4 acc[4][2];
  const f32x4 zz = {0.0f,0.0f,0.0f,0.0f};
#pragma unroll
  for (int i = 0; i < 4; ++i)
#pragma unroll
    for (int j = 0; j < 2; ++j) acc[i][j] = zz;

  u16x8 ra[4], rb[2];
  auto loadk = [&](int k0) {
#pragma unroll
    for (int s = 0; s < 4; ++s) {
      int idx = s*256 + t, row = idx >> 3, ch = idx & 7;
      ra[s] = *reinterpret_cast<const u16x8*>(
          Zb + (size_t)(row0 + row)*256 + k0 + ch*8);
    }
#pragma unroll
    for (int s = 0; s < 2; ++s) {
      int idx = s*256 + t, row = idx >> 3, ch = idx & 7;
      rb[s] = *reinterpret_cast<const u16x8*>(
          W2M + ((size_t)l*OUTD + n0 + row)*256 + k0 + ch*8);
    }
  };
  auto stage = [&](int cb) {
#pragma unroll
    for (int s = 0; s < 4; ++s) {
      int idx = s*256 + t, row = idx >> 3, ch = idx & 7;
      *reinterpret_cast<u16x8*>(&sA[cb][SWZ(row, ch*8)]) = ra[s];
    }
#pragma unroll
    for (int s = 0; s < 2; ++s) {
      int idx = s*256 + t, row = idx >> 3, ch = idx & 7;
      *reinterpret_cast<u16x8*>(&sB[cb][SWZ(row, ch*8)]) = rb[s];
    }
  };

  int cur = 0;
  loadk(0);
  for (int k0 = 0; k0 < 256; k0 += 64) {
    stage(cur);
    asm volatile("s_waitcnt lgkmcnt(0)" ::: "memory");
    __builtin_amdgcn_s_barrier();
    if (k0 + 64 < 256) loadk(k0 + 64);
    __builtin_amdgcn_s_setprio(1);
#pragma unroll
    for (int kc = 0; kc < 2; ++kc) {
      bf16x8 af[4];
#pragma unroll
      for (int i = 0; i < 4; ++i) {
        int rl = waveM*64 + i*16 + lcol;
        af[i] = *reinterpret_cast<const bf16x8*>(&sA[cur][SWZ(rl, kc*32 + quad*8)]);
      }
#pragma unroll
      for (int jj = 0; jj < 2; ++jj) {
        int jl = waveJ*32 + jj*16 + lcol;
        bf16x8 bf = *reinterpret_cast<const bf16x8*>(&sB[cur][SWZ(jl, kc*32 + quad*8)]);
#pragma unroll
        for (int i = 0; i < 4; ++i)
          acc[i][jj] = __builtin_amdgcn_mfma_f32_16x16x32_bf16(af[i], bf, acc[i][jj], 0, 0, 0);
      }
    }
    __builtin_amdgcn_s_setprio(0);
    cur ^= 1;
  }
  // epilogue: + bias diff, store bf16 into OUTT
#pragma unroll
  for (int jj = 0; jj < 2; ++jj) {
    int o = n0 + waveJ*32 + jj*16 + lcol;
    float bd = ld1(eab2, l*OUTD + o, f32) - ld1(egb2, l*OUTD + o, f32);
#pragma unroll
    for (int i = 0; i < 4; ++i)
#pragma unroll
      for (int g = 0; g < 4; ++g) {
        int r = row0 + waveM*64 + i*16 + quad*4 + g;
        OUTT[(size_t)r*KP + o] = f2b(acc[i][jj][g] + bd);
      }
  }
}

// tension -> OUTT col 512 (bf16); zero pad cols 513..543; tsum += sumsq(row)
__global__ void k_tension(u16* __restrict__ OUTT, float* __restrict__ tsum) {
  int row = blockIdx.x, t = threadIdx.x;
  u16* p = OUTT + (size_t)row*KP;
  float v0 = b2f(p[t]), v1 = b2f(p[t+256]);
  float s = v0*v0 + v1*v1;
#pragma unroll
  for (int off = 32; off > 0; off >>= 1) s += __shfl_down(s, off, 64);
  __shared__ float red[4];
  if ((t & 63) == 0) red[t >> 6] = s;
  __syncthreads();
  if (t == 0) {
    float tot = red[0] + red[1] + red[2] + red[3];
    p[512] = f2b(tot * (1.0f/512.0f));
    atomicAdd(tsum, tot);
  }
  if (t < 31) p[513 + t] = 0;
}

// ---------------- fused MFMA GRU v9: global_load_lds DMA staging ----------
// 25-step unified schedule (9 GEMM1 + 16 GEMM2), dbuf LDS (2 x 40 KB).
// Staging = 10 global_load_lds width-16 per thread-chunkset: LINEAR LDS dest
// (wave-uniform base + lane*16) + INVERSE-swizzled per-lane global source
// (rule #21), so LDS contents are bit-identical to the SWZ layout the MFMA
// reads. Zero staging VGPRs/VALU -> no spill (R7/R8's 40MB scratch traffic).
// Schedule: vmcnt(0) -> barrier -> issue DMA(s+1 -> buf^1) -> MFMA(buf).
// Issue-after-barrier removes the WAR hazard on the other buffer.
// GEMM1 tail (s==8, kw=32): DMA lanes predicated on ku<32; kc=1 MFMA skipped.
#define GRUISSUE(s, cb) do {                                                   \
    _Pragma("unroll")                                                          \
    for (int q = 0; q < 10; ++q) {                                             \
      lu32* ldst = (lu32*)&sS[cb][(wid*10 + q)*512];                           \
      if ((s) < 9) {                                                           \
        if ((s) != 8 || kuq[q] < 32)                                           \
          __builtin_amdgcn_global_load_lds((gu32*)(q1[q] + (s)*64),            \
                                           ldst, 16, 0, 0);                    \
      } else {                                                                 \
        __builtin_amdgcn_global_load_lds((gu32*)(q2[q] + ((s)-9)*64),          \
                                         ldst, 16, 0, 0);                      \
      }                                                                        \
    }                                                                          \
  } while (0)

__global__ __launch_bounds__(256, 2) void k_gru_mfma(
    const u16* __restrict__ OUTT, const u16* __restrict__ HB,
    const u16* __restrict__ WihP, const u16* __restrict__ WhhP,
    const void* __restrict__ H,
    const float* __restrict__ bs_r, const float* __restrict__ bs_z,
    const float* __restrict__ bn_i, const float* __restrict__ bn_h,
    const int* __restrict__ dflag, void* __restrict__ outv) {
  const bool f32 = dflag[0] != 0;
  // one region per buffer: u16 [0,8192) = A (128 rows x 64), [8192,20480) = B
  // (3 bands x 64 rows x 64). 2 x 40 KB = 80 KB -> 2 blocks/CU.
  __shared__ __align__(16) u16 sS[2][20480];
  int t = threadIdx.x;
  // XCD swizzle (512 blocks, 512%8==0 -> bijective): xg = XCD id.
  int bid = blockIdx.x;
  int xg = bid & 7, inner = bid >> 3;      // inner 0..63
  int l = xg & 3, jG = xg >> 2;
  int rbi = inner & 7, jbl = inner >> 3;   // 8 row-blocks, 8 j-blocks
  int row0 = (l*8 + rbi) * 128;
  int j0   = (jG*8 + jbl) * 64;
  int wid = t >> 6, lane = t & 63;
  int waveM = wid & 1, waveJ = wid >> 1;   // 2x2 waves over 128x64
  int quad = lane >> 4, lcol = lane & 15;

  f32x4 acc[4][4][2];   // band {r,z,i_n,h_n} x 4 m-frags x 2 j-frags (AGPRs)
  const f32x4 zz = {0.0f,0.0f,0.0f,0.0f};
#pragma unroll
  for (int b = 0; b < 4; ++b)
#pragma unroll
    for (int i = 0; i < 4; ++i)
#pragma unroll
      for (int j = 0; j < 2; ++j) acc[b][i][j] = zz;

  // per-lane DMA source pointers (inverse-swizzled), per chunk q:
  // chunk c = wid*10+q covers LDS u16 [c*512,(c+1)*512); lane covers 8 u16.
  const u16* q1[10];   // GEMM1 sources (OUTT / WihP, stride KP)
  const u16* q2[10];   // GEMM2 sources (HB / WhhP, stride HID)
  int kuq[10];
#pragma unroll
  for (int q = 0; q < 10; ++q) {
    int c = wid*10 + q;
    int cu = c*512 + lane*8;
    if (cu < 8192) {                       // A region: row in [0,128)
      int row = cu >> 6, ks = cu & 63;
      int ku = ks ^ ((row & 7) << 3);
      kuq[q] = ku;
      q1[q] = OUTT + (size_t)(row0 + row)*KP + ku;
      q2[q] = HB   + (size_t)(row0 + row)*HID + ku;
    } else {                               // B region: band x 64 rows
      int ub = cu - 8192;
      int rowf = ub >> 6, ks = ub & 63;
      int band = rowf >> 6, brow = rowf & 63;
      int ku = ks ^ ((brow & 7) << 3);
      kuq[q] = ku;
      size_t gr = (size_t)l*G3 + band*1024 + j0 + brow;
      q1[q] = WihP + gr*KP + ku;
      q2[q] = WhhP + gr*HID + ku;
    }
  }

  auto domfma_kc = [&](int cb, bool g2, int kc) {
    bf16x8 af[4];
#pragma unroll
    for (int i = 0; i < 4; ++i) {
      int rl = waveM*64 + i*16 + lcol;
      af[i] = *reinterpret_cast<const bf16x8*>(&sS[cb][SWZ(rl, kc*32 + quad*8)]);
    }
#pragma unroll
    for (int b = 0; b < 3; ++b) {
      int ai = (g2 && b == 2) ? 3 : b;
#pragma unroll
      for (int jj = 0; jj < 2; ++jj) {
        int jl = waveJ*32 + jj*16 + lcol;
        bf16x8 bf = *reinterpret_cast<const bf16x8*>(
            &sS[cb][8192 + b*4096 + SWZ(jl, kc*32 + quad*8)]);
#pragma unroll
        for (int i = 0; i < 4; ++i)
          acc[ai][i][jj] = __builtin_amdgcn_mfma_f32_16x16x32_bf16(
              af[i], bf, acc[ai][i][jj], 0, 0, 0);
      }
    }
  };

  const int NS = 25;   // 9 (GEMM1, K=544) + 16 (GEMM2, K=1024)
  int cur = 0;
  GRUISSUE(0, 0);
  for (int s = 0; s < NS; ++s) {
    asm volatile("s_waitcnt vmcnt(0)" ::: "memory");   // my DMAs for buf[cur] done
    __builtin_amdgcn_s_barrier();                      // everyone's done
    if (s + 1 < NS) GRUISSUE(s + 1, cur ^ 1);          // safe: prior reads drained
    __builtin_amdgcn_s_setprio(1);
    domfma_kc(cur, s >= 9, 0);
    if (s != 8) domfma_kc(cur, s >= 9, 1);             // skip stale half at tail
    __builtin_amdgcn_s_setprio(0);
    cur ^= 1;
  }
  // ---- epilogue: gates -> new_h into d_out hh region (exact f32 h blend) ----
#pragma unroll
  for (int i = 0; i < 4; ++i)
#pragma unroll
    for (int jj = 0; jj < 2; ++jj) {
      int j = j0 + waveJ*32 + jj*16 + lcol;
      float br = bs_r[l*HID + j], bz = bs_z[l*HID + j];
      float bi = bn_i[l*HID + j], bh = bn_h[l*HID + j];
#pragma unroll
      for (int g = 0; g < 4; ++g) {
        int r = row0 + waveM*64 + i*16 + quad*4 + g;
        float rg = sigm(acc[0][i][jj][g] + br);
        float zg = sigm(acc[1][i][jj][g] + bz);
        float ng = tanhf(acc[2][i][jj][g] + bi + rg*(acc[3][i][jj][g] + bh));
        float hv = ld1(H, (size_t)r*HID + j, f32);
        st1(outv, 513 + (size_t)r*HID + j, (1.0f - zg)*ng + zg*hv, f32);
      }
    }
}

// ---------------- level means (split-C atomics; lm holds SUMS, scaled by consumers) ----
__global__ void k_lm_acc(const void* __restrict__ outv, const int* __restrict__ dflag,
                         float* __restrict__ lm) {
  const bool f32 = dflag[0] != 0;
  int l = blockIdx.x, cc = blockIdx.y, t = threadIdx.x;
  float s0=0.f, s1=0.f, s2=0.f, s3=0.f;
  for (int c = cc*16; c < cc*16 + 16; ++c) {
    size_t base = 513 + (size_t)(l*CPL + c)*HID;
    s0 += ld1(outv, base + t,       f32);
    s1 += ld1(outv, base + 256 + t, f32);
    s2 += ld1(outv, base + 512 + t, f32);
    s3 += ld1(outv, base + 768 + t, f32);
  }
  atomicAdd(&lm[l*HID + t],       s0);
  atomicAdd(&lm[l*HID + 256 + t], s1);
  atomicAdd(&lm[l*HID + 512 + t], s2);
  atomicAdd(&lm[l*HID + 768 + t], s3);
}

// ---------------- predictors (split-K atomics; SCL folds the 1/1024 mean) ----
__global__ void k_pz_acc(const float* __restrict__ lm, const void* __restrict__ pW1,
                         const int* __restrict__ dflag, float* __restrict__ pz) {
  const bool f32 = dflag[0] != 0;
  int lv = blockIdx.x, mb = blockIdx.y, kc = blockIdx.z;
  int m = mb*256 + threadIdx.x;
  float acc = 0.0f;
  int i0 = kc*32;
  const float* lmp = lm + (lv + 1)*HID;
  for (int i = i0; i < i0 + 32; ++i)
    acc += lmp[i] * ld1(pW1, ((size_t)lv*HID + i)*HID + m, f32);
  atomicAdd(&pz[lv*HID + m], acc * SCL);
}
// pz holds raw accumulated sums; bias+relu applied on read here (k_pzfin folded)
__global__ void k_pe_acc(const float* __restrict__ pz, const void* __restrict__ pb1,
                         const void* __restrict__ pW2,
                         const int* __restrict__ dflag, float* __restrict__ pe) {
  const bool f32 = dflag[0] != 0;
  int lv = blockIdx.x, ob = blockIdx.y, kc = blockIdx.z;
  int o = ob*256 + threadIdx.x;
  float acc = 0.0f;
  int m0 = kc*32;
  for (int m = m0; m < m0 + 32; ++m) {
    float v = pz[lv*HID + m] + ld1(pb1, lv*HID + m, f32);
    v = v > 0.0f ? v : 0.0f;
    acc += v * ld1(pW2, ((size_t)lv*HID + m)*HID + o, f32);
  }
  atomicAdd(&pe[lv*HID + o], acc);
}

// k_pefin folded in: pe_t = (pe_raw + pb2 - lm*SCL) * 0.05
__global__ void k_addc_gop(const float* __restrict__ lm, const float* __restrict__ pe,
                           const void* __restrict__ pb2, const int* __restrict__ dflag,
                           float* __restrict__ addc, float* __restrict__ gop) {
  const bool f32 = dflag[0] != 0;
  int j = blockIdx.x*256 + threadIdx.x;
  float pe0 = (pe[j]        + ld1(pb2, j,        f32) - lm[j]*SCL)        * 0.05f;
  float pe1 = (pe[1024 + j] + ld1(pb2, 1024 + j, f32) - lm[1024 + j]*SCL) * 0.05f;
  float pe2 = (pe[2048 + j] + ld1(pb2, 2048 + j, f32) - lm[2048 + j]*SCL) * 0.05f;
  float d0 = pe0, d1 = pe1 - 0.5f*pe0, d2 = pe2 - 0.5f*pe1, d3 = -0.5f*pe2;
  float l0 = lm[j]*SCL, l1 = lm[1024 + j]*SCL, l2 = lm[2048 + j]*SCL, l3 = lm[3072 + j]*SCL;
  addc[j]        = 0.2775f*l0 + d0;
  addc[1024 + j] = 0.2775f*l1 + d1;
  addc[2048 + j] = 0.2775f*l2 + d2;
  addc[3072 + j] = 0.2775f*l3 + d3;
  gop[j] = 0.25f*((l0 + d0) + (l1 + d1) + (l2 + d2) + (l3 + d3));
}

__global__ void k_comb_acc(const float* __restrict__ lm, const void* __restrict__ peiW,
                           const int* __restrict__ dflag, float* __restrict__ comb) {
  const bool f32 = dflag[0] != 0;
  int ob = blockIdx.x, kc = blockIdx.y;
  int o = ob*256 + threadIdx.x;
  float acc = 0.0f;
  int i0 = kc*128;
  for (int i = i0; i < i0 + 128; ++i)
    acc += lm[i] * ld1(peiW, (size_t)i*OUTD + o, f32);
  atomicAdd(&comb[o], acc * SCL);
}
__global__ void k_fin(const float* __restrict__ comb, const void* __restrict__ peib,
                      const float* __restrict__ tsum, const int* __restrict__ dflag,
                      void* __restrict__ outv) {
  const bool f32 = dflag[0] != 0;
  int o = blockIdx.x*256 + threadIdx.x;
  st1(outv, o, comb[o] + ld1(peib, o, f32), f32);
  if (o == 0) st1(outv, 512, tsum[0] * (1.0f/(4096.0f*512.0f)), f32);
}

__global__ void k_hh(void* __restrict__ outv, const float* __restrict__ addc,
                     const float* __restrict__ gop, const int* __restrict__ step,
                     const int* __restrict__ dflag) {
  const bool f32 = dflag[0] != 0;
  int row = blockIdx.x, t = threadIdx.x;
  int l = row >> 10, c = row & 1023;
  bool debate = (step[0] > 5) && (c < 256);
  size_t base = 513 + (size_t)row*HID;
#pragma unroll
  for (int k = 0; k < 4; ++k) {
    int j = t + k*256;
    float v = 0.7225f * ld1(outv, base + j, f32) + addc[l*HID + j];
    if (debate) v = 0.85f*v + 0.15f*gop[j];
    st1(outv, base + j, v, f32);
  }
}

extern "C" void kernel_launch(void* const* d_in, const int* in_sizes, int n_in,
                              void* d_out, int out_size, void* d_ws, size_t ws_size,
                              hipStream_t stream) {
  (void)in_sizes; (void)n_in; (void)out_size; (void)ws_size;
  const void* x    = d_in[0];
  const void* hid  = d_in[1];
  const void* eaW1 = d_in[2];
  const void* eab1 = d_in[3];
  const void* eaW2 = d_in[4];
  const void* eab2 = d_in[5];
  const void* egW1 = d_in[6];
  const void* egb1 = d_in[7];
  const void* egW2 = d_in[8];
  const void* egb2 = d_in[9];
  const void* gWih = d_in[10];
  const void* gWhh = d_in[11];
  const void* gbih = d_in[12];
  const void* gbhh = d_in[13];
  const void* pW1  = d_in[14];
  const void* pb1  = d_in[15];
  const void* pW2  = d_in[16];
  const void* pb2  = d_in[17];
  const void* peiW = d_in[18];
  const void* peib = d_in[19];
  const int*  step = (const int*)d_in[20];

  // ---- workspace layout (~54.6 MB) ----
  float* wsf = (float*)d_ws;
  float* tsum    = wsf + 0;       // 64
  float* baseacc = wsf + 64;      // 1024
  float* lm      = wsf + 1088;    // 4096
  float* pz      = wsf + 5184;    // 3072
  float* pe      = wsf + 8256;    // 3072
  float* comb    = wsf + 11328;   // 512 (+pad to 12288)
  int*   dflag   = (int*)(wsf + 12288);  // 64
  float* bs_r    = wsf + 12352;   // 4096
  float* bs_z    = wsf + 16448;   // 4096
  float* bn_i    = wsf + 20544;   // 4096
  float* bn_h    = wsf + 24640;   // 4096
  float* addc    = wsf + 28736;   // 4096
  float* gop     = wsf + 32832;   // 1024
  u16* Zb   = (u16*)(wsf + 33856);        // 4096*256
  u16* OUTT = Zb + (size_t)4096*256;      // 4096*544
  u16* WihP = OUTT + (size_t)4096*KP;     // 12288*544
  u16* HB   = WihP + (size_t)12288*KP;    // 4096*1024  (bf16 hiddens)
  u16* WhhP = HB   + (size_t)4096*1024;   // 12288*1024 (bf16 Whh)
  u16* W2M  = WhhP + (size_t)12288*1024;  // 4*512*256  (bf16 packed W2, 1 MB)
  // W1T (4*256*1024 u16 = 2.1 MB) overlays OUTT: dead once k_z finishes,
  // before k_outm writes OUTT.
  u16* W1T  = OUTT;

  k_detect   <<<dim3(1),        dim3(256), 0, stream>>>(x, dflag);
  k_prep     <<<dim3(64),       dim3(256), 0, stream>>>(wsf, gbih, gbhh, dflag,
                                                        bs_r, bs_z, bn_i, bn_h);
  k_prep_wih <<<dim3(12288),    dim3(256), 0, stream>>>(gWih, dflag, WihP);
  k_prep_cvt <<<dim3(8192),     dim3(256), 0, stream>>>(gWhh, hid, dflag, WhhP, HB);
  k_prep_w1t <<<dim3(4,2,16),   dim3(256), 0, stream>>>(eaW1, egW1, dflag, W1T);
  k_prep_w2m <<<dim3(4,2,4),    dim3(256), 0, stream>>>(eaW2, egW2, dflag, W2M);
  k_base_acc <<<dim3(4,2,4),    dim3(128), 0, stream>>>(x, eaW1, egW1, dflag, baseacc);
  k_z_mfma   <<<dim3(64,4),     dim3(256), 0, stream>>>(HB, W1T, eab1, egb1,
                                                        baseacc, dflag, Zb);
  k_outm     <<<dim3(32,8),     dim3(256), 0, stream>>>(Zb, W2M, eab2, egb2,
                                                        dflag, OUTT);
  k_tension  <<<dim3(4096),     dim3(256), 0, stream>>>(OUTT, tsum);
  k_gru_mfma <<<dim3(512),      dim3(256), 0, stream>>>(OUTT, HB, WihP, WhhP, hid,
                                                        bs_r, bs_z, bn_i, bn_h,
                                                        dflag, d_out);
  k_lm_acc   <<<dim3(4,64),     dim3(256), 0, stream>>>(d_out, dflag, lm);
  k_pz_acc   <<<dim3(3,4,32),   dim3(256), 0, stream>>>(lm, pW1, dflag, pz);
  k_pe_acc   <<<dim3(3,4,32),   dim3(256), 0, stream>>>(pz, pb1, pW2, dflag, pe);
  k_addc_gop <<<dim3(4),        dim3(256), 0, stream>>>(lm, pe, pb2, dflag, addc, gop);
  k_comb_acc <<<dim3(2,32),     dim3(256), 0, stream>>>(lm, peiW, dflag, comb);
  k_fin      <<<dim3(2),        dim3(256), 0, stream>>>(comb, peib, tsum, dflag, d_out);
  k_hh       <<<dim3(4096),     dim3(256), 0, stream>>>(d_out, addc, gop, step, dflag);
}